// Round 2
// baseline (2631.320 us; speedup 1.0000x reference)
//
#include <hip/hip_runtime.h>
#include <hip/hip_bf16.h>
#include <math.h>

#define S_ 128
#define B_ 64
#define W_ 16
#define CE_ 30
#define FN_ 4
#define WE_ 300
#define FEAT_ 420
#define C_ 512
#define NT_ 20

// workspace layout (floats)
#define WF_OFF 0
#define WF_SZ (S_*B_*FEAT_)              // 3,440,640
#define H0_OFF (WF_OFF + WF_SZ)
#define H_SZ (B_*C_*S_)                  // 4,194,304
#define H1_OFF (H0_OFF + H_SZ)
#define EM_OFF (H1_OFF + H_SZ)
#define EM_SZ (S_*B_*NT_)
#define NLL_OFF (EM_OFF + EM_SZ)

// ---------------- K1a: word embedding gather -> wf[:, :300] ----------------
__global__ void k_word_gather(const int* __restrict__ words,
                              const float* __restrict__ word_emb,
                              float* __restrict__ wf) {
    int n = blockIdx.x;                  // n = s*B + b  (same index for words and wf row)
    int wid = words[n];
    int t = threadIdx.x;
    if (t < WE_ / 4) {                   // 75 float4 = 300 floats
        const float4* src = (const float4*)(word_emb + (size_t)wid * WE_);
        float4* dst = (float4*)(wf + (size_t)n * FEAT_);
        dst[t] = src[t];
    }
}

// ---------------- K1b: char depthwise CNN + maxpool -> wf[:, 300:420] ------
__global__ void k_char_cnn(const int* __restrict__ chars,
                           const float* __restrict__ char_emb,
                           const float* __restrict__ cw,
                           const float* __restrict__ cb,
                           float* __restrict__ wf) {
    int n = blockIdx.x;                  // n = b*S + s  (chars layout)
    int b = n >> 7;
    int s = n & 127;
    __shared__ int cidx[W_];
    int t = threadIdx.x;
    if (t < W_) cidx[t] = chars[n * W_ + t];
    __syncthreads();
    if (t < CE_ * FN_) {                 // 120 output channels
        int g = t >> 2;                  // group = o / FN, input channel = g
        float w0 = cw[t*3+0], w1 = cw[t*3+1], w2 = cw[t*3+2];
        float x[W_];
        #pragma unroll
        for (int j = 0; j < W_; ++j) x[j] = char_emb[cidx[j] * CE_ + g];
        float m = -INFINITY;
        #pragma unroll
        for (int j = 0; j < W_ - 2; ++j) {
            float v = x[j]*w0 + x[j+1]*w1 + x[j+2]*w2;
            m = fmaxf(m, v);
        }
        wf[(size_t)(s * B_ + b) * FEAT_ + WE_ + t] = m + cb[t];
    }
}

// ---------------- K2: linear 420 -> 512, out h (B,C,S) ---------------------
__global__ __launch_bounds__(256) void k_linear(const float* __restrict__ wf,
                                                const float* __restrict__ lin_w,
                                                const float* __restrict__ lin_b,
                                                float* __restrict__ h0) {
    __shared__ float As[16][68];         // [kk][c]
    __shared__ float Bs[64][17];         // [n][kk]
    int n0 = blockIdx.x * 64;            // n = b*S + s
    int c0 = blockIdx.y * 64;
    int t = threadIdx.x;
    int cc = (t & 15) * 4;
    int nn = (t >> 4) * 4;
    float acc[4][4] = {};
    for (int k0 = 0; k0 < FEAT_; k0 += 16) {
        {   // A tile: lin_w[k0+kk][c0+c4..]
            int kk = t >> 4;
            int c4 = (t & 15) * 4;
            float4 v = make_float4(0.f, 0.f, 0.f, 0.f);
            if (k0 + kk < FEAT_)
                v = *(const float4*)(lin_w + (size_t)(k0 + kk) * C_ + c0 + c4);
            *(float4*)&As[kk][c4] = v;
        }
        {   // B tile: wf row (s*B+b), features k0+fq..+3
            int nl = t >> 2;
            int fq = (t & 3) * 4;
            int n = n0 + nl;
            int row = (n & 127) * B_ + (n >> 7);
            float4 v = make_float4(0.f, 0.f, 0.f, 0.f);
            if (k0 + fq < FEAT_)
                v = *(const float4*)(wf + (size_t)row * FEAT_ + k0 + fq);
            Bs[nl][fq+0] = v.x; Bs[nl][fq+1] = v.y;
            Bs[nl][fq+2] = v.z; Bs[nl][fq+3] = v.w;
        }
        __syncthreads();
        #pragma unroll
        for (int kk = 0; kk < 16; ++kk) {
            float4 a4 = *(float4*)&As[kk][cc];
            float b0 = Bs[nn+0][kk], b1 = Bs[nn+1][kk];
            float b2 = Bs[nn+2][kk], b3 = Bs[nn+3][kk];
            acc[0][0] += a4.x*b0; acc[0][1] += a4.x*b1; acc[0][2] += a4.x*b2; acc[0][3] += a4.x*b3;
            acc[1][0] += a4.y*b0; acc[1][1] += a4.y*b1; acc[1][2] += a4.y*b2; acc[1][3] += a4.y*b3;
            acc[2][0] += a4.z*b0; acc[2][1] += a4.z*b1; acc[2][2] += a4.z*b2; acc[2][3] += a4.z*b3;
            acc[3][0] += a4.w*b0; acc[3][1] += a4.w*b1; acc[3][2] += a4.w*b2; acc[3][3] += a4.w*b3;
        }
        __syncthreads();
    }
    int n = n0 + nn;
    int b = n >> 7, s = n & 127;
    #pragma unroll
    for (int i = 0; i < 4; ++i) {
        int c = c0 + cc + i;
        float bb = lin_b[c];
        float4 o;
        o.x = acc[i][0] + bb; o.y = acc[i][1] + bb;
        o.z = acc[i][2] + bb; o.w = acc[i][3] + bb;
        *(float4*)(h0 + ((size_t)b * C_ + c) * S_ + s) = o;
    }
}

// ---------------- K3: fused GLU conv layer (k=3, pad 1) --------------------
__global__ __launch_bounds__(256) void k_glu_conv(const float* __restrict__ hin,
                                                  const float* __restrict__ conv_w,
                                                  const float* __restrict__ conv_b,
                                                  float* __restrict__ hout,
                                                  int l) {
    __shared__ float hs[16][68];         // [kk][s0-1+j], j in [0,66)
    __shared__ float wa[16][192];        // [kk][c*3+k]  a-half weights
    __shared__ float wg[16][192];        // [kk][c*3+k]  g-half weights
    int s0 = blockIdx.x * 64;
    int c0 = blockIdx.y * 64;
    int b  = blockIdx.z;
    int t  = threadIdx.x;
    int cc = (t & 15) * 4;
    int ss = (t >> 4) * 4;
    float aacc[4][4] = {};
    float gacc[4][4] = {};
    const float* wbase = conv_w + (size_t)l * 1024 * C_ * 3;

    for (int i0 = 0; i0 < C_; i0 += 16) {
        // stage input slab: 16 channels x 66 positions (with halo, zero-padded)
        for (int idx = t; idx < 16 * 66; idx += 256) {
            int kk = idx / 66;
            int j  = idx - kk * 66;
            int sg = s0 - 1 + j;
            float v = 0.f;
            if (sg >= 0 && sg < S_)
                v = hin[((size_t)b * C_ + (i0 + kk)) * S_ + sg];
            hs[kk][j] = v;
        }
        // stage weights: both halves, 64 out-ch x 16 in-ch x 3 taps each
        {
            int ol = t >> 2, part = t & 3;
            #pragma unroll
            for (int half = 0; half < 2; ++half) {
                int o = c0 + ol + half * 512;
                const float* gp = wbase + ((size_t)o * C_ + i0) * 3 + part * 12;
                float4 f0 = *(const float4*)(gp);
                float4 f1 = *(const float4*)(gp + 4);
                float4 f2 = *(const float4*)(gp + 8);
                float f[12] = {f0.x,f0.y,f0.z,f0.w,f1.x,f1.y,f1.z,f1.w,f2.x,f2.y,f2.z,f2.w};
                float (*dst)[192] = half ? wg : wa;
                #pragma unroll
                for (int j = 0; j < 12; ++j) {
                    int kk = part * 4 + j / 3;
                    int kr = j % 3;
                    dst[kk][ol * 3 + kr] = f[j];
                }
            }
        }
        __syncthreads();
        #pragma unroll
        for (int kk = 0; kk < 16; ++kk) {
            float hv[6];
            float4 h4 = *(float4*)&hs[kk][ss];
            float2 h2 = *(float2*)&hs[kk][ss + 4];
            hv[0]=h4.x; hv[1]=h4.y; hv[2]=h4.z; hv[3]=h4.w; hv[4]=h2.x; hv[5]=h2.y;
            float wva[12], wvg[12];
            *(float4*)&wva[0] = *(float4*)&wa[kk][cc*3];
            *(float4*)&wva[4] = *(float4*)&wa[kk][cc*3+4];
            *(float4*)&wva[8] = *(float4*)&wa[kk][cc*3+8];
            *(float4*)&wvg[0] = *(float4*)&wg[kk][cc*3];
            *(float4*)&wvg[4] = *(float4*)&wg[kk][cc*3+4];
            *(float4*)&wvg[8] = *(float4*)&wg[kk][cc*3+8];
            #pragma unroll
            for (int ci = 0; ci < 4; ++ci) {
                #pragma unroll
                for (int si = 0; si < 4; ++si) {
                    aacc[ci][si] += wva[ci*3+0]*hv[si] + wva[ci*3+1]*hv[si+1] + wva[ci*3+2]*hv[si+2];
                    gacc[ci][si] += wvg[ci*3+0]*hv[si] + wvg[ci*3+1]*hv[si+1] + wvg[ci*3+2]*hv[si+2];
                }
            }
        }
        __syncthreads();
    }
    // epilogue: GLU + residual + scale
    const float rs = 0.70710678118654752f;
    #pragma unroll
    for (int ci = 0; ci < 4; ++ci) {
        int c = c0 + cc + ci;
        float ba = conv_b[l * 1024 + c];
        float bg = conv_b[l * 1024 + 512 + c];
        float4 r4 = *(const float4*)(hin + ((size_t)b * C_ + c) * S_ + s0 + ss);
        float rr[4] = {r4.x, r4.y, r4.z, r4.w};
        float o[4];
        #pragma unroll
        for (int si = 0; si < 4; ++si) {
            float a = aacc[ci][si] + ba;
            float g = gacc[ci][si] + bg;
            float sg = 1.f / (1.f + expf(-g));
            o[si] = (a * sg + rr[si]) * rs;
        }
        float4 ov; ov.x = o[0]; ov.y = o[1]; ov.z = o[2]; ov.w = o[3];
        *(float4*)(hout + ((size_t)b * C_ + c) * S_ + s0 + ss) = ov;
    }
}

// ---------------- K4: emissions 512 -> 20 ----------------------------------
__global__ __launch_bounds__(256) void k_emis(const float* __restrict__ h,
                                              const float* __restrict__ fc_w,
                                              const float* __restrict__ fc_b,
                                              float* __restrict__ emis) {
    __shared__ float hsE[16][128];
    __shared__ float wsE[16][20];
    int b = blockIdx.x;
    int t = threadIdx.x;
    int tg = t >> 7;                     // 0 or 1 -> tags [0,10) / [10,20)
    int s  = t & 127;
    float acc[10] = {};
    for (int c0 = 0; c0 < C_; c0 += 16) {
        {
            int kk = t >> 5;
            int s4 = (t & 31) * 4;
            #pragma unroll
            for (int r = 0; r < 2; ++r) {
                int kkr = kk + r * 8;
                *(float4*)&hsE[kkr][s4] =
                    *(const float4*)(h + ((size_t)b * C_ + c0 + kkr) * S_ + s4);
            }
        }
        // FIX: 320 entries, 256 threads -> strided loop (rows 13..15 were garbage)
        for (int idx = t; idx < 16 * NT_; idx += 256) {
            int kk = idx / NT_, tt = idx - kk * NT_;
            wsE[kk][tt] = fc_w[(size_t)(c0 + kk) * NT_ + tt];
        }
        __syncthreads();
        #pragma unroll
        for (int kk = 0; kk < 16; ++kk) {
            float hv = hsE[kk][s];
            #pragma unroll
            for (int j = 0; j < 10; ++j) acc[j] += hv * wsE[kk][tg * 10 + j];
        }
        __syncthreads();
    }
    #pragma unroll
    for (int j = 0; j < 10; ++j)
        emis[((size_t)s * B_ + b) * NT_ + tg * 10 + j] = acc[j] + fc_b[tg * 10 + j];
}

// ---------------- K5: CRF NLL per batch ------------------------------------
__global__ void k_crf_nll(const float* __restrict__ emis,
                          const int* __restrict__ words,
                          const int* __restrict__ tags,
                          const float* __restrict__ tstart,
                          const float* __restrict__ tend,
                          const float* __restrict__ ttrans,
                          float* __restrict__ nll) {
    int b = blockIdx.x;
    int j = threadIdx.x;
    __shared__ float alphaL[NT_];
    bool act = j < NT_;
    float tc[NT_];
    float alpha = 0.f;
    if (act) {
        #pragma unroll
        for (int i = 0; i < NT_; ++i) tc[i] = ttrans[i * NT_ + j];
        alpha = tstart[j] + emis[(size_t)b * NT_ + j];
        alphaL[j] = alpha;
    }
    // numerator (gold path score) + mask count
    float part = 0.f;
    int cnt = 0;
    for (int tt = j; tt < S_; tt += 64) {
        int tgc = tags[tt * B_ + b];
        bool m = words[tt * B_ + b] != 0;
        cnt += m ? 1 : 0;
        if (tt == 0) {
            part += tstart[tgc] + emis[(size_t)b * NT_ + tgc];
        } else if (m) {
            int tgp = tags[(tt - 1) * B_ + b];
            part += ttrans[tgp * NT_ + tgc] + emis[((size_t)tt * B_ + b) * NT_ + tgc];
        }
    }
    #pragma unroll
    for (int o = 32; o >= 1; o >>= 1) {
        part += __shfl_down(part, o);
        cnt  += __shfl_down(cnt, o);
    }
    __syncthreads();
    // forward scan with logsumexp
    for (int tt = 1; tt < S_; ++tt) {
        if (act) {
            float mx = -INFINITY;
            #pragma unroll
            for (int i = 0; i < NT_; ++i) mx = fmaxf(mx, alphaL[i] + tc[i]);
            float sm = 0.f;
            #pragma unroll
            for (int i = 0; i < NT_; ++i) sm += expf(alphaL[i] + tc[i] - mx);
            float nxt = mx + logf(sm) + emis[((size_t)tt * B_ + b) * NT_ + j];
            bool m = words[tt * B_ + b] != 0;
            alpha = m ? nxt : alpha;
        }
        __syncthreads();
        if (act) alphaL[j] = alpha;
        __syncthreads();
    }
    // logz = logsumexp(alpha + end)
    float v = act ? (alpha + tend[j]) : -INFINITY;
    float mx = v;
    #pragma unroll
    for (int o = 32; o >= 1; o >>= 1) mx = fmaxf(mx, __shfl_down(mx, o));
    mx = __shfl(mx, 0);
    float se = act ? expf(v - mx) : 0.f;
    #pragma unroll
    for (int o = 32; o >= 1; o >>= 1) se += __shfl_down(se, o);
    if (j == 0) {
        float logz = mx + logf(se);
        float num = part;
        int last = cnt - 1;
        num += tend[tags[last * B_ + b]];
        nll[b] = logz - num;              // = -(num - logz)
    }
}

// ---------------- K6: Viterbi per batch ------------------------------------
__global__ void k_viterbi(const float* __restrict__ emis,
                          const int* __restrict__ words,
                          const float* __restrict__ tstart,
                          const float* __restrict__ tend,
                          const float* __restrict__ ttrans,
                          float* __restrict__ out) {
    int b = blockIdx.x;
    int j = threadIdx.x;
    __shared__ float scoreL[NT_];
    __shared__ unsigned char bpL[S_ - 1][NT_];
    bool act = j < NT_;
    float tc[NT_];
    float score = 0.f;
    if (act) {
        #pragma unroll
        for (int i = 0; i < NT_; ++i) tc[i] = ttrans[i * NT_ + j];
        score = tstart[j] + emis[(size_t)b * NT_ + j];
        scoreL[j] = score;
    }
    __syncthreads();
    for (int tt = 1; tt < S_; ++tt) {
        if (act) {
            float best = -INFINITY;
            int bi = 0;
            #pragma unroll
            for (int i = 0; i < NT_; ++i) {       // strict > keeps FIRST max (jnp.argmax)
                float v = scoreL[i] + tc[i];
                if (v > best) { best = v; bi = i; }
            }
            bool m = words[tt * B_ + b] != 0;
            float nxt = best + emis[((size_t)tt * B_ + b) * NT_ + j];
            score = m ? nxt : score;
            bpL[tt - 1][j] = m ? (unsigned char)bi : (unsigned char)j;
        }
        __syncthreads();
        if (act) scoreL[j] = score;
        __syncthreads();
    }
    if (j == 0) {
        float best = -INFINITY;
        int bt = 0;
        for (int i = 0; i < NT_; ++i) {
            float v = scoreL[i] + tend[i];
            if (v > best) { best = v; bt = i; }
        }
        int tag = bt;
        for (int tt = S_ - 1; tt >= 1; --tt) {
            out[tt * B_ + b] = (float)tag;
            tag = bpL[tt - 1][tag];
        }
        out[b] = (float)tag;
    }
}

// ---------------- K7: final loss reduce ------------------------------------
__global__ void k_loss(const float* __restrict__ nll, float* __restrict__ out) {
    float v = nll[threadIdx.x];
    #pragma unroll
    for (int o = 32; o >= 1; o >>= 1) v += __shfl_down(v, o);
    if (threadIdx.x == 0) out[S_ * B_] = v;
}

extern "C" void kernel_launch(void* const* d_in, const int* in_sizes, int n_in,
                              void* d_out, int out_size, void* d_ws, size_t ws_size,
                              hipStream_t stream) {
    (void)in_sizes; (void)n_in; (void)out_size; (void)ws_size;
    const int*   words     = (const int*)d_in[0];
    const int*   chars     = (const int*)d_in[1];
    const int*   tags      = (const int*)d_in[2];
    const float* word_emb  = (const float*)d_in[3];
    const float* char_emb  = (const float*)d_in[4];
    const float* ccw       = (const float*)d_in[5];
    const float* ccb       = (const float*)d_in[6];
    const float* lin_w     = (const float*)d_in[7];
    const float* lin_b     = (const float*)d_in[8];
    const float* conv_w    = (const float*)d_in[9];
    const float* conv_b    = (const float*)d_in[10];
    const float* fc_w      = (const float*)d_in[11];
    const float* fc_b      = (const float*)d_in[12];
    const float* crf_start = (const float*)d_in[13];
    const float* crf_end   = (const float*)d_in[14];
    const float* crf_trans = (const float*)d_in[15];

    float* ws  = (float*)d_ws;
    float* wf  = ws + WF_OFF;
    float* h0  = ws + H0_OFF;
    float* h1  = ws + H1_OFF;
    float* em  = ws + EM_OFF;
    float* nll = ws + NLL_OFF;
    float* out = (float*)d_out;

    k_word_gather<<<S_ * B_, 128, 0, stream>>>(words, word_emb, wf);
    k_char_cnn<<<B_ * S_, 128, 0, stream>>>(chars, char_emb, ccw, ccb, wf);
    k_linear<<<dim3(128, 8), 256, 0, stream>>>(wf, lin_w, lin_b, h0);
    k_glu_conv<<<dim3(2, 8, B_), 256, 0, stream>>>(h0, conv_w, conv_b, h1, 0);
    k_glu_conv<<<dim3(2, 8, B_), 256, 0, stream>>>(h1, conv_w, conv_b, h0, 1);
    k_glu_conv<<<dim3(2, 8, B_), 256, 0, stream>>>(h0, conv_w, conv_b, h1, 2);
    k_emis<<<B_, 256, 0, stream>>>(h1, fc_w, fc_b, em);
    k_crf_nll<<<B_, 64, 0, stream>>>(em, words, tags, crf_start, crf_end, crf_trans, nll);
    k_viterbi<<<B_, 64, 0, stream>>>(em, words, crf_start, crf_end, crf_trans, out);
    k_loss<<<1, 64, 0, stream>>>(nll, out);
}

// Round 3
// 662.583 us; speedup vs baseline: 3.9713x; 3.9713x over previous
//
#include <hip/hip_runtime.h>
#include <math.h>

typedef unsigned short ushort_t;
typedef short bf16x8 __attribute__((ext_vector_type(8)));
typedef float f32x4 __attribute__((ext_vector_type(4)));
typedef unsigned short u16x8 __attribute__((ext_vector_type(8)));

#define S_ 128
#define B_ 64
#define W_ 16
#define CE_ 30
#define FN_ 4
#define WE_ 300
#define FEAT_ 420
#define C_ 512
#define NT_ 20

// ---- workspace layout (float units) ----
#define WF_OFF   0                       // 3,440,640 floats
#define EM_OFF   3440640                 // 163,840
#define NLL_OFF  3604480                 // 64
#define HI0_OFF  3604608                 // each h buffer: 64*130*512 bf16 = 2,129,920 floats
#define HBUF_F   2129920
#define LO0_OFF  (HI0_OFF + HBUF_F)
#define HI1_OFF  (LO0_OFF + HBUF_F)
#define LO1_OFF  (HI1_OFF + HBUF_F)
#define WHI_OFF  (LO1_OFF + HBUF_F)      // 3*1024*1536 bf16 = 2,359,296 floats
#define WSP_F    2359296
#define WLO_OFF  (WHI_OFF + WSP_F)
#define WLAYER   (1024*1536)             // ushort elems per layer

__device__ __forceinline__ float b2f(ushort_t h) {
    unsigned u = ((unsigned)h) << 16;
    float f; __builtin_memcpy(&f, &u, 4); return f;
}
__device__ __forceinline__ ushort_t f2b(float f) {   // round-to-nearest-even
    unsigned u; __builtin_memcpy(&u, &f, 4);
    unsigned r = (u + 0x7FFFu + ((u >> 16) & 1u)) >> 16;
    return (ushort_t)r;
}
__device__ __forceinline__ void gload16(const void* g, void* l) {
    __builtin_amdgcn_global_load_lds((const __attribute__((address_space(1))) void*)g,
                                     (__attribute__((address_space(3))) void*)l,
                                     16, 0, 0);
}

// ---------------- K1a: word embedding gather -> wf[:, :300] ----------------
__global__ void k_word_gather(const int* __restrict__ words,
                              const float* __restrict__ word_emb,
                              float* __restrict__ wf) {
    int n = blockIdx.x;                  // n = s*B + b
    int wid = words[n];
    int t = threadIdx.x;
    if (t < WE_ / 4) {
        const float4* src = (const float4*)(word_emb + (size_t)wid * WE_);
        float4* dst = (float4*)(wf + (size_t)n * FEAT_);
        dst[t] = src[t];
    }
}

// ---------------- K1b: char depthwise CNN + maxpool -> wf[:, 300:420] ------
__global__ void k_char_cnn(const int* __restrict__ chars,
                           const float* __restrict__ char_emb,
                           const float* __restrict__ cw,
                           const float* __restrict__ cb,
                           float* __restrict__ wf) {
    int n = blockIdx.x;                  // n = b*S + s
    int b = n >> 7;
    int s = n & 127;
    __shared__ int cidx[W_];
    int t = threadIdx.x;
    if (t < W_) cidx[t] = chars[n * W_ + t];
    __syncthreads();
    if (t < CE_ * FN_) {
        int g = t >> 2;
        float w0 = cw[t*3+0], w1 = cw[t*3+1], w2 = cw[t*3+2];
        float x[W_];
        #pragma unroll
        for (int j = 0; j < W_; ++j) x[j] = char_emb[cidx[j] * CE_ + g];
        float m = -INFINITY;
        #pragma unroll
        for (int j = 0; j < W_ - 2; ++j) {
            float v = x[j]*w0 + x[j+1]*w1 + x[j+2]*w2;
            m = fmaxf(m, v);
        }
        wf[(size_t)(s * B_ + b) * FEAT_ + WE_ + t] = m + cb[t];
    }
}

// ---------------- split conv weights into bf16 hi/lo, k' = kr*512+ci -------
__global__ void k_split_w(const float* __restrict__ conv_w,
                          ushort_t* __restrict__ Whi, ushort_t* __restrict__ Wlo) {
    size_t i = (size_t)blockIdx.x * 256 + threadIdx.x;   // 3*1024*1536 total
    int ci = (int)(i & 511);
    int kr = (int)((i >> 9) % 3);
    size_t lo_ = i / 1536;                               // l*1024 + o
    float v = conv_w[lo_ * 1536 + (size_t)ci * 3 + kr];
    ushort_t hi = f2b(v);
    ushort_t lo = f2b(v - b2f(hi));
    Whi[i] = hi; Wlo[i] = lo;
}

// ---------------- zero the pad rows (s'=0, s'=129) of h buffers ------------
__global__ void k_zero_pad(ushort_t* b0, ushort_t* b1, ushort_t* b2, ushort_t* b3) {
    ushort_t* bufs[4] = {b0, b1, b2, b3};
    ushort_t* buf = bufs[blockIdx.y];
    int b = blockIdx.x;
    int t = threadIdx.x;                 // 256 threads; row = 512 bf16 = 256 uints
    unsigned* r0 = (unsigned*)(buf + ((size_t)b * 130 + 0) * 512);
    unsigned* r1 = (unsigned*)(buf + ((size_t)b * 130 + 129) * 512);
    r0[t] = 0u; r1[t] = 0u;
}

// ---------------- K2: linear 420 -> 512, out h (b,s,c) bf16 hi/lo ----------
__global__ __launch_bounds__(256) void k_linear(const float* __restrict__ wf,
                                                const float* __restrict__ lin_w,
                                                const float* __restrict__ lin_b,
                                                ushort_t* __restrict__ hhi,
                                                ushort_t* __restrict__ hlo) {
    __shared__ float As[16][68];
    __shared__ float Bs[64][17];
    int n0 = blockIdx.x * 64;            // n = b*S + s
    int c0 = blockIdx.y * 64;
    int t = threadIdx.x;
    int cc = (t & 15) * 4;
    int nn = (t >> 4) * 4;
    float acc[4][4] = {};
    for (int k0 = 0; k0 < FEAT_; k0 += 16) {
        {
            int kk = t >> 4;
            int c4 = (t & 15) * 4;
            float4 v = make_float4(0.f, 0.f, 0.f, 0.f);
            if (k0 + kk < FEAT_)
                v = *(const float4*)(lin_w + (size_t)(k0 + kk) * C_ + c0 + c4);
            *(float4*)&As[kk][c4] = v;
        }
        {
            int nl = t >> 2;
            int fq = (t & 3) * 4;
            int n = n0 + nl;
            int row = (n & 127) * B_ + (n >> 7);
            float4 v = make_float4(0.f, 0.f, 0.f, 0.f);
            if (k0 + fq < FEAT_)
                v = *(const float4*)(wf + (size_t)row * FEAT_ + k0 + fq);
            Bs[nl][fq+0] = v.x; Bs[nl][fq+1] = v.y;
            Bs[nl][fq+2] = v.z; Bs[nl][fq+3] = v.w;
        }
        __syncthreads();
        #pragma unroll
        for (int kk = 0; kk < 16; ++kk) {
            float4 a4 = *(float4*)&As[kk][cc];
            float b0 = Bs[nn+0][kk], b1 = Bs[nn+1][kk];
            float b2 = Bs[nn+2][kk], b3 = Bs[nn+3][kk];
            acc[0][0] += a4.x*b0; acc[0][1] += a4.x*b1; acc[0][2] += a4.x*b2; acc[0][3] += a4.x*b3;
            acc[1][0] += a4.y*b0; acc[1][1] += a4.y*b1; acc[1][2] += a4.y*b2; acc[1][3] += a4.y*b3;
            acc[2][0] += a4.z*b0; acc[2][1] += a4.z*b1; acc[2][2] += a4.z*b2; acc[2][3] += a4.z*b3;
            acc[3][0] += a4.w*b0; acc[3][1] += a4.w*b1; acc[3][2] += a4.w*b2; acc[3][3] += a4.w*b3;
        }
        __syncthreads();
    }
    int n = n0 + nn;
    int b = n >> 7, s = n & 127;
    float4 bb = *(const float4*)(lin_b + c0 + cc);
    #pragma unroll
    for (int j = 0; j < 4; ++j) {
        float x0 = acc[0][j] + bb.x;
        float x1 = acc[1][j] + bb.y;
        float x2 = acc[2][j] + bb.z;
        float x3 = acc[3][j] + bb.w;
        ushort4 h4, l4;
        h4.x = f2b(x0); l4.x = f2b(x0 - b2f(h4.x));
        h4.y = f2b(x1); l4.y = f2b(x1 - b2f(h4.y));
        h4.z = f2b(x2); l4.z = f2b(x2 - b2f(h4.z));
        h4.w = f2b(x3); l4.w = f2b(x3 - b2f(h4.w));
        size_t dst = ((size_t)b * 130 + s + j + 1) * 512 + c0 + cc;
        *(ushort4*)(hhi + dst) = h4;
        *(ushort4*)(hlo + dst) = l4;
    }
}

// ---------------- K3: GLU conv layer as split-bf16 MFMA GEMM ---------------
// BM=128 rows = 64 a-ch + 64 g-ch; BN=128 (one batch, all s); BK=32.
// K' = 3 passes x (kr 0..2) x (ci 0..511):  Whi*hhi + Whi*hlo + Wlo*hhi.
__global__ __launch_bounds__(256) void k_conv_gemm(
    const ushort_t* __restrict__ Wh, const ushort_t* __restrict__ Wl,
    const ushort_t* __restrict__ Hh, const ushort_t* __restrict__ Hl,
    const float* __restrict__ cb,          // conv_b + l*1024
    ushort_t* __restrict__ Oh, ushort_t* __restrict__ Ol)
{
    __shared__ float g_lds[128 * 68];      // 34816 B; first 16 KB aliased as A/B tiles
    short* As = (short*)g_lds;             // [128][32] bf16
    short* Bs = (short*)g_lds + 4096;      // [128][32] bf16

    const int b    = blockIdx.y;
    const int co0  = blockIdx.x << 6;      // 64 output channels per block
    const int t    = threadIdx.x;
    const int w    = t >> 6;               // wave 0..3
    const int lane = t & 63;
    const int wr   = w >> 1;               // 0: a-rows, 1: g-rows
    const int wc   = w & 1;                // s half

    // staging constants (2 x 16-row instructions per wave per tile)
    const int srow0 = (w << 5) + (lane >> 2);
    const int srow1 = srow0 + 16;
    const int j0 = (lane & 3) ^ ((srow0 >> 1) & 3);
    const int j1 = (lane & 3) ^ ((srow1 >> 1) & 3);
    const int coA0 = (srow0 < 64) ? (co0 + srow0) : (512 + co0 + srow0 - 64);
    const int coA1 = (srow1 < 64) ? (co0 + srow1) : (512 + co0 + srow1 - 64);
    const size_t aoff0 = (size_t)coA0 * 1536 + j0 * 8;
    const size_t aoff1 = (size_t)coA1 * 1536 + j1 * 8;
    const size_t hoff0 = ((size_t)b * 130 + srow0) * 512 + j0 * 8;
    const size_t hoff1 = ((size_t)b * 130 + srow1) * 512 + j1 * 8;
    short* ldsA = As + (w << 10);
    short* ldsB = Bs + (w << 10);

    // fragment read offsets (source-swizzle matched: kg' = kg ^ ((row>>1)&3))
    const int lr = lane & 15, kg = lane >> 4;
    int aro[4], bro[4];
    #pragma unroll
    for (int m = 0; m < 4; ++m) { int r = (wr << 6) + (m << 4) + lr; aro[m] = (r << 5) + ((kg ^ ((r >> 1) & 3)) << 3); }
    #pragma unroll
    for (int n = 0; n < 4; ++n) { int r = (wc << 6) + (n << 4) + lr; bro[n] = (r << 5) + ((kg ^ ((r >> 1) & 3)) << 3); }

    f32x4 acc[4][4];
    #pragma unroll
    for (int m = 0; m < 4; ++m)
        #pragma unroll
        for (int n = 0; n < 4; ++n) acc[m][n] = (f32x4){0.f, 0.f, 0.f, 0.f};

    const ushort_t* Ap[3] = {Wh, Wh, Wl};
    const ushort_t* Bp[3] = {Hh, Hl, Hh};

    for (int p = 0; p < 3; ++p) {
        const ushort_t* wsrc = Ap[p];
        const ushort_t* hsrc = Bp[p];
        for (int kr = 0; kr < 3; ++kr) {
            const size_t hk0 = hoff0 + (size_t)kr * 512;   // row s+kr in padded layout
            const size_t hk1 = hoff1 + (size_t)kr * 512;
            for (int ci0 = 0; ci0 < 512; ci0 += 32) {
                const int kb = kr * 512 + ci0;
                gload16(wsrc + aoff0 + kb, ldsA);
                gload16(wsrc + aoff1 + kb, ldsA + 512);
                gload16(hsrc + hk0 + ci0, ldsB);
                gload16(hsrc + hk1 + ci0, ldsB + 512);
                __syncthreads();
                bf16x8 av[4], bv[4];
                #pragma unroll
                for (int m = 0; m < 4; ++m) av[m] = *(const bf16x8*)(As + aro[m]);
                #pragma unroll
                for (int n = 0; n < 4; ++n) bv[n] = *(const bf16x8*)(Bs + bro[n]);
                #pragma unroll
                for (int m = 0; m < 4; ++m)
                    #pragma unroll
                    for (int n = 0; n < 4; ++n)
                        acc[m][n] = __builtin_amdgcn_mfma_f32_16x16x32_bf16(av[m], bv[n], acc[m][n], 0, 0, 0);
                __syncthreads();
            }
        }
    }

    // ---- fused GLU epilogue: g-waves hand their acc to a-waves via LDS ----
    const float rs = 0.70710678118654752f;
    if (wr == 1) {
        #pragma unroll
        for (int m = 0; m < 4; ++m) {
            const int co_l = (m << 4) + (kg << 2);
            float4 bg = *(const float4*)(cb + 512 + co0 + co_l);
            #pragma unroll
            for (int n = 0; n < 4; ++n) {
                const int s_l = (wc << 6) + (n << 4) + lr;
                float4 gv;
                gv.x = acc[m][n][0] + bg.x;
                gv.y = acc[m][n][1] + bg.y;
                gv.z = acc[m][n][2] + bg.z;
                gv.w = acc[m][n][3] + bg.w;
                *(float4*)&g_lds[s_l * 68 + co_l] = gv;
            }
        }
    }
    __syncthreads();
    if (wr == 0) {
        #pragma unroll
        for (int m = 0; m < 4; ++m) {
            const int co_l = (m << 4) + (kg << 2);
            float4 ba = *(const float4*)(cb + co0 + co_l);
            #pragma unroll
            for (int n = 0; n < 4; ++n) {
                const int s_l = (wc << 6) + (n << 4) + lr;
                float4 gv = *(const float4*)&g_lds[s_l * 68 + co_l];
                size_t dst = ((size_t)b * 130 + s_l + 1) * 512 + co0 + co_l;
                ushort4 rh = *(const ushort4*)(Hh + dst);
                ushort4 rl = *(const ushort4*)(Hl + dst);
                float a0 = acc[m][n][0] + ba.x, g0 = gv.x;
                float a1 = acc[m][n][1] + ba.y, g1 = gv.y;
                float a2 = acc[m][n][2] + ba.z, g2 = gv.z;
                float a3 = acc[m][n][3] + ba.w, g3 = gv.w;
                float o0 = (a0 / (1.f + expf(-g0)) + (b2f(rh.x) + b2f(rl.x))) * rs;
                float o1 = (a1 / (1.f + expf(-g1)) + (b2f(rh.y) + b2f(rl.y))) * rs;
                float o2 = (a2 / (1.f + expf(-g2)) + (b2f(rh.z) + b2f(rl.z))) * rs;
                float o3 = (a3 / (1.f + expf(-g3)) + (b2f(rh.w) + b2f(rl.w))) * rs;
                ushort4 h4, l4;
                h4.x = f2b(o0); l4.x = f2b(o0 - b2f(h4.x));
                h4.y = f2b(o1); l4.y = f2b(o1 - b2f(h4.y));
                h4.z = f2b(o2); l4.z = f2b(o2 - b2f(h4.z));
                h4.w = f2b(o3); l4.w = f2b(o3 - b2f(h4.w));
                *(ushort4*)(Oh + dst) = h4;
                *(ushort4*)(Ol + dst) = l4;
            }
        }
    }
}

// ---------------- K4: emissions 512 -> 20 (h in (b,s,c) bf16 hi/lo) --------
__global__ __launch_bounds__(256) void k_emis2(const ushort_t* __restrict__ hhi,
                                               const ushort_t* __restrict__ hlo,
                                               const float* __restrict__ fc_w,
                                               const float* __restrict__ fc_b,
                                               float* __restrict__ emis) {
    __shared__ float hsE[128][33];
    __shared__ float wsE[32][20];
    int b = blockIdx.x, t = threadIdx.x;
    int tg = t >> 7, s = t & 127;
    float acc[10] = {};
    for (int c0 = 0; c0 < C_; c0 += 32) {
        #pragma unroll
        for (int i = 0; i < 2; ++i) {
            int flat = t + i * 256;
            int row = flat >> 2, ch = (flat & 3) * 8;
            size_t src = ((size_t)b * 130 + row + 1) * 512 + c0 + ch;
            u16x8 vh = *(const u16x8*)(hhi + src);
            u16x8 vl = *(const u16x8*)(hlo + src);
            #pragma unroll
            for (int k = 0; k < 8; ++k) hsE[row][ch + k] = b2f(vh[k]) + b2f(vl[k]);
        }
        for (int idx = t; idx < 32 * NT_; idx += 256) {
            int kk = idx / NT_, tt = idx - kk * NT_;
            wsE[kk][tt] = fc_w[(size_t)(c0 + kk) * NT_ + tt];
        }
        __syncthreads();
        #pragma unroll
        for (int kk = 0; kk < 32; ++kk) {
            float hv = hsE[s][kk];
            #pragma unroll
            for (int j = 0; j < 10; ++j) acc[j] += hv * wsE[kk][tg * 10 + j];
        }
        __syncthreads();
    }
    #pragma unroll
    for (int j = 0; j < 10; ++j)
        emis[((size_t)s * B_ + b) * NT_ + tg * 10 + j] = acc[j] + fc_b[tg * 10 + j];
}

// ---------------- K5: CRF NLL per batch ------------------------------------
__global__ void k_crf_nll(const float* __restrict__ emis,
                          const int* __restrict__ words,
                          const int* __restrict__ tags,
                          const float* __restrict__ tstart,
                          const float* __restrict__ tend,
                          const float* __restrict__ ttrans,
                          float* __restrict__ nll) {
    int b = blockIdx.x;
    int j = threadIdx.x;
    __shared__ float alphaL[NT_];
    bool act = j < NT_;
    float tc[NT_];
    float alpha = 0.f;
    if (act) {
        #pragma unroll
        for (int i = 0; i < NT_; ++i) tc[i] = ttrans[i * NT_ + j];
        alpha = tstart[j] + emis[(size_t)b * NT_ + j];
        alphaL[j] = alpha;
    }
    float part = 0.f;
    int cnt = 0;
    for (int tt = j; tt < S_; tt += 64) {
        int tgc = tags[tt * B_ + b];
        bool m = words[tt * B_ + b] != 0;
        cnt += m ? 1 : 0;
        if (tt == 0) {
            part += tstart[tgc] + emis[(size_t)b * NT_ + tgc];
        } else if (m) {
            int tgp = tags[(tt - 1) * B_ + b];
            part += ttrans[tgp * NT_ + tgc] + emis[((size_t)tt * B_ + b) * NT_ + tgc];
        }
    }
    #pragma unroll
    for (int o = 32; o >= 1; o >>= 1) {
        part += __shfl_down(part, o);
        cnt  += __shfl_down(cnt, o);
    }
    __syncthreads();
    for (int tt = 1; tt < S_; ++tt) {
        if (act) {
            float mx = -INFINITY;
            #pragma unroll
            for (int i = 0; i < NT_; ++i) mx = fmaxf(mx, alphaL[i] + tc[i]);
            float sm = 0.f;
            #pragma unroll
            for (int i = 0; i < NT_; ++i) sm += expf(alphaL[i] + tc[i] - mx);
            float nxt = mx + logf(sm) + emis[((size_t)tt * B_ + b) * NT_ + j];
            bool m = words[tt * B_ + b] != 0;
            alpha = m ? nxt : alpha;
        }
        __syncthreads();
        if (act) alphaL[j] = alpha;
        __syncthreads();
    }
    float v = act ? (alpha + tend[j]) : -INFINITY;
    float mx = v;
    #pragma unroll
    for (int o = 32; o >= 1; o >>= 1) mx = fmaxf(mx, __shfl_down(mx, o));
    mx = __shfl(mx, 0);
    float se = act ? expf(v - mx) : 0.f;
    #pragma unroll
    for (int o = 32; o >= 1; o >>= 1) se += __shfl_down(se, o);
    if (j == 0) {
        float logz = mx + logf(se);
        float num = part;
        int last = cnt - 1;
        num += tend[tags[last * B_ + b]];
        nll[b] = logz - num;
    }
}

// ---------------- K6: Viterbi per batch ------------------------------------
__global__ void k_viterbi(const float* __restrict__ emis,
                          const int* __restrict__ words,
                          const float* __restrict__ tstart,
                          const float* __restrict__ tend,
                          const float* __restrict__ ttrans,
                          float* __restrict__ out) {
    int b = blockIdx.x;
    int j = threadIdx.x;
    __shared__ float scoreL[NT_];
    __shared__ unsigned char bpL[S_ - 1][NT_];
    bool act = j < NT_;
    float tc[NT_];
    float score = 0.f;
    if (act) {
        #pragma unroll
        for (int i = 0; i < NT_; ++i) tc[i] = ttrans[i * NT_ + j];
        score = tstart[j] + emis[(size_t)b * NT_ + j];
        scoreL[j] = score;
    }
    __syncthreads();
    for (int tt = 1; tt < S_; ++tt) {
        if (act) {
            float best = -INFINITY;
            int bi = 0;
            #pragma unroll
            for (int i = 0; i < NT_; ++i) {
                float v = scoreL[i] + tc[i];
                if (v > best) { best = v; bi = i; }
            }
            bool m = words[tt * B_ + b] != 0;
            float nxt = best + emis[((size_t)tt * B_ + b) * NT_ + j];
            score = m ? nxt : score;
            bpL[tt - 1][j] = m ? (unsigned char)bi : (unsigned char)j;
        }
        __syncthreads();
        if (act) scoreL[j] = score;
        __syncthreads();
    }
    if (j == 0) {
        float best = -INFINITY;
        int bt = 0;
        for (int i = 0; i < NT_; ++i) {
            float v = scoreL[i] + tend[i];
            if (v > best) { best = v; bt = i; }
        }
        int tag = bt;
        for (int tt = S_ - 1; tt >= 1; --tt) {
            out[tt * B_ + b] = (float)tag;
            tag = bpL[tt - 1][tag];
        }
        out[b] = (float)tag;
    }
}

// ---------------- K7: final loss reduce ------------------------------------
__global__ void k_loss(const float* __restrict__ nll, float* __restrict__ out) {
    float v = nll[threadIdx.x];
    #pragma unroll
    for (int o = 32; o >= 1; o >>= 1) v += __shfl_down(v, o);
    if (threadIdx.x == 0) out[S_ * B_] = v;
}

extern "C" void kernel_launch(void* const* d_in, const int* in_sizes, int n_in,
                              void* d_out, int out_size, void* d_ws, size_t ws_size,
                              hipStream_t stream) {
    (void)in_sizes; (void)n_in; (void)out_size; (void)ws_size;
    const int*   words     = (const int*)d_in[0];
    const int*   chars     = (const int*)d_in[1];
    const int*   tags      = (const int*)d_in[2];
    const float* word_emb  = (const float*)d_in[3];
    const float* char_emb  = (const float*)d_in[4];
    const float* ccw       = (const float*)d_in[5];
    const float* ccb       = (const float*)d_in[6];
    const float* lin_w     = (const float*)d_in[7];
    const float* lin_b     = (const float*)d_in[8];
    const float* conv_w    = (const float*)d_in[9];
    const float* conv_b    = (const float*)d_in[10];
    const float* fc_w      = (const float*)d_in[11];
    const float* fc_b      = (const float*)d_in[12];
    const float* crf_start = (const float*)d_in[13];
    const float* crf_end   = (const float*)d_in[14];
    const float* crf_trans = (const float*)d_in[15];

    float* ws   = (float*)d_ws;
    float* wf   = ws + WF_OFF;
    float* em   = ws + EM_OFF;
    float* nll  = ws + NLL_OFF;
    ushort_t* hi0 = (ushort_t*)(ws + HI0_OFF);
    ushort_t* lo0 = (ushort_t*)(ws + LO0_OFF);
    ushort_t* hi1 = (ushort_t*)(ws + HI1_OFF);
    ushort_t* lo1 = (ushort_t*)(ws + LO1_OFF);
    ushort_t* whi = (ushort_t*)(ws + WHI_OFF);
    ushort_t* wlo = (ushort_t*)(ws + WLO_OFF);
    float* out  = (float*)d_out;

    k_word_gather<<<S_ * B_, 128, 0, stream>>>(words, word_emb, wf);
    k_char_cnn<<<B_ * S_, 128, 0, stream>>>(chars, char_emb, ccw, ccb, wf);
    k_split_w<<<18432, 256, 0, stream>>>(conv_w, whi, wlo);
    k_zero_pad<<<dim3(64, 4), 256, 0, stream>>>(hi0, lo0, hi1, lo1);
    k_linear<<<dim3(128, 8), 256, 0, stream>>>(wf, lin_w, lin_b, hi0, lo0);

    k_conv_gemm<<<dim3(8, 64), 256, 0, stream>>>(whi,            wlo,            hi0, lo0, conv_b,        hi1, lo1);
    k_conv_gemm<<<dim3(8, 64), 256, 0, stream>>>(whi + WLAYER,   wlo + WLAYER,   hi1, lo1, conv_b + 1024, hi0, lo0);
    k_conv_gemm<<<dim3(8, 64), 256, 0, stream>>>(whi + 2*WLAYER, wlo + 2*WLAYER, hi0, lo0, conv_b + 2048, hi1, lo1);

    k_emis2<<<B_, 256, 0, stream>>>(hi1, lo1, fc_w, fc_b, em);
    k_crf_nll<<<B_, 64, 0, stream>>>(em, words, tags, crf_start, crf_end, crf_trans, nll);
    k_viterbi<<<B_, 64, 0, stream>>>(em, words, crf_start, crf_end, crf_trans, out);
    k_loss<<<1, 64, 0, stream>>>(nll, out);
}

// Round 4
// 517.534 us; speedup vs baseline: 5.0843x; 1.2803x over previous
//
#include <hip/hip_runtime.h>
#include <math.h>

typedef unsigned short ushort_t;
typedef short bf16x8 __attribute__((ext_vector_type(8)));
typedef float f32x4 __attribute__((ext_vector_type(4)));
typedef unsigned short u16x8 __attribute__((ext_vector_type(8)));

#define S_ 128
#define B_ 64
#define W_ 16
#define CE_ 30
#define FN_ 4
#define WE_ 300
#define FEAT_ 420
#define C_ 512
#define NT_ 20

#define LOG2E_ 1.44269504088896340736f
#define LN2_   0.69314718055994530942f

// ---- workspace layout (float units) ----
#define WF_OFF   0                       // 3,440,640 floats
#define EM_OFF   3440640                 // 163,840
#define NLL_OFF  3604480                 // 64
#define HI0_OFF  3604608                 // each h buffer: 64*130*512 bf16 = 2,129,920 floats
#define HBUF_F   2129920
#define LO0_OFF  (HI0_OFF + HBUF_F)
#define HI1_OFF  (LO0_OFF + HBUF_F)
#define LO1_OFF  (HI1_OFF + HBUF_F)
#define WHI_OFF  (LO1_OFF + HBUF_F)      // 3*1024*1536 bf16 = 2,359,296 floats
#define WSP_F    2359296
#define WLO_OFF  (WHI_OFF + WSP_F)
#define WLAYER   (1024*1536)             // ushort elems per layer

__device__ __forceinline__ float b2f(ushort_t h) {
    unsigned u = ((unsigned)h) << 16;
    float f; __builtin_memcpy(&f, &u, 4); return f;
}
__device__ __forceinline__ ushort_t f2b(float f) {   // round-to-nearest-even
    unsigned u; __builtin_memcpy(&u, &f, 4);
    unsigned r = (u + 0x7FFFu + ((u >> 16) & 1u)) >> 16;
    return (ushort_t)r;
}
__device__ __forceinline__ void gload16(const void* g, void* l) {
    __builtin_amdgcn_global_load_lds((const __attribute__((address_space(1))) void*)g,
                                     (__attribute__((address_space(3))) void*)l,
                                     16, 0, 0);
}
__device__ __forceinline__ float max20(const float* v) {
    float m0=fmaxf(v[0],v[1]),  m1=fmaxf(v[2],v[3]),  m2=fmaxf(v[4],v[5]),
          m3=fmaxf(v[6],v[7]),  m4=fmaxf(v[8],v[9]),  m5=fmaxf(v[10],v[11]),
          m6=fmaxf(v[12],v[13]),m7=fmaxf(v[14],v[15]),m8=fmaxf(v[16],v[17]),
          m9=fmaxf(v[18],v[19]);
    return fmaxf(fmaxf(fmaxf(fmaxf(m0,m1),fmaxf(m2,m3)),
                       fmaxf(fmaxf(m4,m5),fmaxf(m6,m7))), fmaxf(m8,m9));
}
__device__ __forceinline__ float sum20(const float* v) {
    float s0=v[0]+v[1],  s1=v[2]+v[3],  s2=v[4]+v[5],  s3=v[6]+v[7],
          s4=v[8]+v[9],  s5=v[10]+v[11],s6=v[12]+v[13],s7=v[14]+v[15],
          s8=v[16]+v[17],s9=v[18]+v[19];
    return (((s0+s1)+(s2+s3))+((s4+s5)+(s6+s7)))+(s8+s9);
}

// ---------------- K1a: word embedding gather -> wf[:, :300] ----------------
__global__ void k_word_gather(const int* __restrict__ words,
                              const float* __restrict__ word_emb,
                              float* __restrict__ wf) {
    int n = blockIdx.x;                  // n = s*B + b
    int wid = words[n];
    int t = threadIdx.x;
    if (t < WE_ / 4) {
        const float4* src = (const float4*)(word_emb + (size_t)wid * WE_);
        float4* dst = (float4*)(wf + (size_t)n * FEAT_);
        dst[t] = src[t];
    }
}

// ---------------- K1b: char depthwise CNN + maxpool -> wf[:, 300:420] ------
__global__ void k_char_cnn(const int* __restrict__ chars,
                           const float* __restrict__ char_emb,
                           const float* __restrict__ cw,
                           const float* __restrict__ cb,
                           float* __restrict__ wf) {
    int n = blockIdx.x;                  // n = b*S + s
    int b = n >> 7;
    int s = n & 127;
    __shared__ int cidx[W_];
    int t = threadIdx.x;
    if (t < W_) cidx[t] = chars[n * W_ + t];
    __syncthreads();
    if (t < CE_ * FN_) {
        int g = t >> 2;
        float w0 = cw[t*3+0], w1 = cw[t*3+1], w2 = cw[t*3+2];
        float x[W_];
        #pragma unroll
        for (int j = 0; j < W_; ++j) x[j] = char_emb[cidx[j] * CE_ + g];
        float m = -INFINITY;
        #pragma unroll
        for (int j = 0; j < W_ - 2; ++j) {
            float v = x[j]*w0 + x[j+1]*w1 + x[j+2]*w2;
            m = fmaxf(m, v);
        }
        wf[(size_t)(s * B_ + b) * FEAT_ + WE_ + t] = m + cb[t];
    }
}

// ---------------- split conv weights into bf16 hi/lo, k' = kr*512+ci -------
__global__ void k_split_w(const float* __restrict__ conv_w,
                          ushort_t* __restrict__ Whi, ushort_t* __restrict__ Wlo) {
    size_t i = (size_t)blockIdx.x * 256 + threadIdx.x;   // 3*1024*1536 total
    int ci = (int)(i & 511);
    int kr = (int)((i >> 9) % 3);
    size_t lo_ = i / 1536;                               // l*1024 + o
    float v = conv_w[lo_ * 1536 + (size_t)ci * 3 + kr];
    ushort_t hi = f2b(v);
    ushort_t lo = f2b(v - b2f(hi));
    Whi[i] = hi; Wlo[i] = lo;
}

// ---------------- zero the pad rows (s'=0, s'=129) of h buffers ------------
__global__ void k_zero_pad(ushort_t* b0, ushort_t* b1, ushort_t* b2, ushort_t* b3) {
    ushort_t* bufs[4] = {b0, b1, b2, b3};
    ushort_t* buf = bufs[blockIdx.y];
    int b = blockIdx.x;
    int t = threadIdx.x;                 // 256 threads; row = 512 bf16 = 256 uints
    unsigned* r0 = (unsigned*)(buf + ((size_t)b * 130 + 0) * 512);
    unsigned* r1 = (unsigned*)(buf + ((size_t)b * 130 + 129) * 512);
    r0[t] = 0u; r1[t] = 0u;
}

// ---------------- K2: linear 420 -> 512, out h (b,s,c) bf16 hi/lo ----------
__global__ __launch_bounds__(256) void k_linear(const float* __restrict__ wf,
                                                const float* __restrict__ lin_w,
                                                const float* __restrict__ lin_b,
                                                ushort_t* __restrict__ hhi,
                                                ushort_t* __restrict__ hlo) {
    __shared__ float As[16][68];
    __shared__ float Bs[64][17];
    int n0 = blockIdx.x * 64;            // n = b*S + s
    int c0 = blockIdx.y * 64;
    int t = threadIdx.x;
    int cc = (t & 15) * 4;
    int nn = (t >> 4) * 4;
    float acc[4][4] = {};
    for (int k0 = 0; k0 < FEAT_; k0 += 16) {
        {
            int kk = t >> 4;
            int c4 = (t & 15) * 4;
            float4 v = make_float4(0.f, 0.f, 0.f, 0.f);
            if (k0 + kk < FEAT_)
                v = *(const float4*)(lin_w + (size_t)(k0 + kk) * C_ + c0 + c4);
            *(float4*)&As[kk][c4] = v;
        }
        {
            int nl = t >> 2;
            int fq = (t & 3) * 4;
            int n = n0 + nl;
            int row = (n & 127) * B_ + (n >> 7);
            float4 v = make_float4(0.f, 0.f, 0.f, 0.f);
            if (k0 + fq < FEAT_)
                v = *(const float4*)(wf + (size_t)row * FEAT_ + k0 + fq);
            Bs[nl][fq+0] = v.x; Bs[nl][fq+1] = v.y;
            Bs[nl][fq+2] = v.z; Bs[nl][fq+3] = v.w;
        }
        __syncthreads();
        #pragma unroll
        for (int kk = 0; kk < 16; ++kk) {
            float4 a4 = *(float4*)&As[kk][cc];
            float b0 = Bs[nn+0][kk], b1 = Bs[nn+1][kk];
            float b2 = Bs[nn+2][kk], b3 = Bs[nn+3][kk];
            acc[0][0] += a4.x*b0; acc[0][1] += a4.x*b1; acc[0][2] += a4.x*b2; acc[0][3] += a4.x*b3;
            acc[1][0] += a4.y*b0; acc[1][1] += a4.y*b1; acc[1][2] += a4.y*b2; acc[1][3] += a4.y*b3;
            acc[2][0] += a4.z*b0; acc[2][1] += a4.z*b1; acc[2][2] += a4.z*b2; acc[2][3] += a4.z*b3;
            acc[3][0] += a4.w*b0; acc[3][1] += a4.w*b1; acc[3][2] += a4.w*b2; acc[3][3] += a4.w*b3;
        }
        __syncthreads();
    }
    int n = n0 + nn;
    int b = n >> 7, s = n & 127;
    float4 bb = *(const float4*)(lin_b + c0 + cc);
    #pragma unroll
    for (int j = 0; j < 4; ++j) {
        float x0 = acc[0][j] + bb.x;
        float x1 = acc[1][j] + bb.y;
        float x2 = acc[2][j] + bb.z;
        float x3 = acc[3][j] + bb.w;
        ushort4 h4, l4;
        h4.x = f2b(x0); l4.x = f2b(x0 - b2f(h4.x));
        h4.y = f2b(x1); l4.y = f2b(x1 - b2f(h4.y));
        h4.z = f2b(x2); l4.z = f2b(x2 - b2f(h4.z));
        h4.w = f2b(x3); l4.w = f2b(x3 - b2f(h4.w));
        size_t dst = ((size_t)b * 130 + s + j + 1) * 512 + c0 + cc;
        *(ushort4*)(hhi + dst) = h4;
        *(ushort4*)(hlo + dst) = l4;
    }
}

// ---------------- K3: GLU conv layer as split-bf16 MFMA GEMM ---------------
__global__ __launch_bounds__(256) void k_conv_gemm(
    const ushort_t* __restrict__ Wh, const ushort_t* __restrict__ Wl,
    const ushort_t* __restrict__ Hh, const ushort_t* __restrict__ Hl,
    const float* __restrict__ cb,          // conv_b + l*1024
    ushort_t* __restrict__ Oh, ushort_t* __restrict__ Ol)
{
    __shared__ float g_lds[128 * 68];      // 34816 B; first 16 KB aliased as A/B tiles
    short* As = (short*)g_lds;             // [128][32] bf16
    short* Bs = (short*)g_lds + 4096;      // [128][32] bf16

    const int b    = blockIdx.y;
    const int co0  = blockIdx.x << 6;      // 64 output channels per block
    const int t    = threadIdx.x;
    const int w    = t >> 6;               // wave 0..3
    const int lane = t & 63;
    const int wr   = w >> 1;               // 0: a-rows, 1: g-rows
    const int wc   = w & 1;                // s half

    const int srow0 = (w << 5) + (lane >> 2);
    const int srow1 = srow0 + 16;
    const int j0 = (lane & 3) ^ ((srow0 >> 1) & 3);
    const int j1 = (lane & 3) ^ ((srow1 >> 1) & 3);
    const int coA0 = (srow0 < 64) ? (co0 + srow0) : (512 + co0 + srow0 - 64);
    const int coA1 = (srow1 < 64) ? (co0 + srow1) : (512 + co0 + srow1 - 64);
    const size_t aoff0 = (size_t)coA0 * 1536 + j0 * 8;
    const size_t aoff1 = (size_t)coA1 * 1536 + j1 * 8;
    const size_t hoff0 = ((size_t)b * 130 + srow0) * 512 + j0 * 8;
    const size_t hoff1 = ((size_t)b * 130 + srow1) * 512 + j1 * 8;
    short* ldsA = As + (w << 10);
    short* ldsB = Bs + (w << 10);

    const int lr = lane & 15, kg = lane >> 4;
    int aro[4], bro[4];
    #pragma unroll
    for (int m = 0; m < 4; ++m) { int r = (wr << 6) + (m << 4) + lr; aro[m] = (r << 5) + ((kg ^ ((r >> 1) & 3)) << 3); }
    #pragma unroll
    for (int n = 0; n < 4; ++n) { int r = (wc << 6) + (n << 4) + lr; bro[n] = (r << 5) + ((kg ^ ((r >> 1) & 3)) << 3); }

    f32x4 acc[4][4];
    #pragma unroll
    for (int m = 0; m < 4; ++m)
        #pragma unroll
        for (int n = 0; n < 4; ++n) acc[m][n] = (f32x4){0.f, 0.f, 0.f, 0.f};

    const ushort_t* Ap[3] = {Wh, Wh, Wl};
    const ushort_t* Bp[3] = {Hh, Hl, Hh};

    for (int p = 0; p < 3; ++p) {
        const ushort_t* wsrc = Ap[p];
        const ushort_t* hsrc = Bp[p];
        for (int kr = 0; kr < 3; ++kr) {
            const size_t hk0 = hoff0 + (size_t)kr * 512;
            const size_t hk1 = hoff1 + (size_t)kr * 512;
            for (int ci0 = 0; ci0 < 512; ci0 += 32) {
                const int kb = kr * 512 + ci0;
                gload16(wsrc + aoff0 + kb, ldsA);
                gload16(wsrc + aoff1 + kb, ldsA + 512);
                gload16(hsrc + hk0 + ci0, ldsB);
                gload16(hsrc + hk1 + ci0, ldsB + 512);
                __syncthreads();
                bf16x8 av[4], bv[4];
                #pragma unroll
                for (int m = 0; m < 4; ++m) av[m] = *(const bf16x8*)(As + aro[m]);
                #pragma unroll
                for (int n = 0; n < 4; ++n) bv[n] = *(const bf16x8*)(Bs + bro[n]);
                #pragma unroll
                for (int m = 0; m < 4; ++m)
                    #pragma unroll
                    for (int n = 0; n < 4; ++n)
                        acc[m][n] = __builtin_amdgcn_mfma_f32_16x16x32_bf16(av[m], bv[n], acc[m][n], 0, 0, 0);
                __syncthreads();
            }
        }
    }

    const float rs = 0.70710678118654752f;
    if (wr == 1) {
        #pragma unroll
        for (int m = 0; m < 4; ++m) {
            const int co_l = (m << 4) + (kg << 2);
            float4 bg = *(const float4*)(cb + 512 + co0 + co_l);
            #pragma unroll
            for (int n = 0; n < 4; ++n) {
                const int s_l = (wc << 6) + (n << 4) + lr;
                float4 gv;
                gv.x = acc[m][n][0] + bg.x;
                gv.y = acc[m][n][1] + bg.y;
                gv.z = acc[m][n][2] + bg.z;
                gv.w = acc[m][n][3] + bg.w;
                *(float4*)&g_lds[s_l * 68 + co_l] = gv;
            }
        }
    }
    __syncthreads();
    if (wr == 0) {
        #pragma unroll
        for (int m = 0; m < 4; ++m) {
            const int co_l = (m << 4) + (kg << 2);
            float4 ba = *(const float4*)(cb + co0 + co_l);
            #pragma unroll
            for (int n = 0; n < 4; ++n) {
                const int s_l = (wc << 6) + (n << 4) + lr;
                float4 gv = *(const float4*)&g_lds[s_l * 68 + co_l];
                size_t dst = ((size_t)b * 130 + s_l + 1) * 512 + co0 + co_l;
                ushort4 rh = *(const ushort4*)(Hh + dst);
                ushort4 rl = *(const ushort4*)(Hl + dst);
                float a0 = acc[m][n][0] + ba.x, g0 = gv.x;
                float a1 = acc[m][n][1] + ba.y, g1 = gv.y;
                float a2 = acc[m][n][2] + ba.z, g2 = gv.z;
                float a3 = acc[m][n][3] + ba.w, g3 = gv.w;
                float o0 = (a0 / (1.f + expf(-g0)) + (b2f(rh.x) + b2f(rl.x))) * rs;
                float o1 = (a1 / (1.f + expf(-g1)) + (b2f(rh.y) + b2f(rl.y))) * rs;
                float o2 = (a2 / (1.f + expf(-g2)) + (b2f(rh.z) + b2f(rl.z))) * rs;
                float o3 = (a3 / (1.f + expf(-g3)) + (b2f(rh.w) + b2f(rl.w))) * rs;
                ushort4 h4, l4;
                h4.x = f2b(o0); l4.x = f2b(o0 - b2f(h4.x));
                h4.y = f2b(o1); l4.y = f2b(o1 - b2f(h4.y));
                h4.z = f2b(o2); l4.z = f2b(o2 - b2f(h4.z));
                h4.w = f2b(o3); l4.w = f2b(o3 - b2f(h4.w));
                *(ushort4*)(Oh + dst) = h4;
                *(ushort4*)(Ol + dst) = l4;
            }
        }
    }
}

// ---------------- K4: emissions 512 -> 20 (h in (b,s,c) bf16 hi/lo) --------
__global__ __launch_bounds__(256) void k_emis2(const ushort_t* __restrict__ hhi,
                                               const ushort_t* __restrict__ hlo,
                                               const float* __restrict__ fc_w,
                                               const float* __restrict__ fc_b,
                                               float* __restrict__ emis) {
    __shared__ float hsE[128][33];
    __shared__ float wsE[32][20];
    int b = blockIdx.x, t = threadIdx.x;
    int tg = t >> 7, s = t & 127;
    float acc[10] = {};
    for (int c0 = 0; c0 < C_; c0 += 32) {
        #pragma unroll
        for (int i = 0; i < 2; ++i) {
            int flat = t + i * 256;
            int row = flat >> 2, ch = (flat & 3) * 8;
            size_t src = ((size_t)b * 130 + row + 1) * 512 + c0 + ch;
            u16x8 vh = *(const u16x8*)(hhi + src);
            u16x8 vl = *(const u16x8*)(hlo + src);
            #pragma unroll
            for (int k = 0; k < 8; ++k) hsE[row][ch + k] = b2f(vh[k]) + b2f(vl[k]);
        }
        for (int idx = t; idx < 32 * NT_; idx += 256) {
            int kk = idx / NT_, tt = idx - kk * NT_;
            wsE[kk][tt] = fc_w[(size_t)(c0 + kk) * NT_ + tt];
        }
        __syncthreads();
        #pragma unroll
        for (int kk = 0; kk < 32; ++kk) {
            float hv = hsE[s][kk];
            #pragma unroll
            for (int j = 0; j < 10; ++j) acc[j] += hv * wsE[kk][tg * 10 + j];
        }
        __syncthreads();
    }
    #pragma unroll
    for (int j = 0; j < 10; ++j)
        emis[((size_t)s * B_ + b) * NT_ + tg * 10 + j] = acc[j] + fc_b[tg * 10 + j];
}

// ---------------- K5: fused CRF NLL (wave 0) + Viterbi (wave 1) ------------
__global__ __launch_bounds__(128) void k_crf(const float* __restrict__ emis,
                                             const int* __restrict__ words,
                                             const int* __restrict__ tags,
                                             const float* __restrict__ tstart,
                                             const float* __restrict__ tend,
                                             const float* __restrict__ ttrans,
                                             float* __restrict__ nll,
                                             float* __restrict__ out) {
    __shared__ float e_lds[S_ * NT_];          // 10240 B
    __shared__ int   bp_lds[(S_ - 1) * NT_];   // 10160 B
    const int b = blockIdx.x;
    const int t = threadIdx.x;

    for (int idx = t; idx < S_ * NT_; idx += 128) {
        int tt = idx / NT_, j = idx - tt * NT_;
        e_lds[idx] = emis[((size_t)tt * B_ + b) * NT_ + j];
    }
    __syncthreads();

    const int ln = t & 63;
    unsigned long long mlo = __ballot(words[ln * B_ + b] != 0);
    unsigned long long mhi = __ballot(words[(64 + ln) * B_ + b] != 0);
    const bool act = ln < NT_;
    const int jc = act ? ln : 0;
    float tc[NT_];
    #pragma unroll
    for (int i = 0; i < NT_; ++i) tc[i] = act ? ttrans[i * NT_ + ln] : 0.f;

    if (t < 64) {
        // ---------- NLL: numerator ----------
        float part = 0.f;
        for (int tt = ln; tt < S_; tt += 64) {
            int tgc = tags[tt * B_ + b];
            bool m = ((tt < 64 ? (mlo >> tt) : (mhi >> (tt - 64))) & 1ull) != 0;
            if (tt == 0) {
                part += tstart[tgc] + e_lds[tgc];
            } else if (m) {
                int tgp = tags[(tt - 1) * B_ + b];
                part += ttrans[tgp * NT_ + tgc] + e_lds[tt * NT_ + tgc];
            }
        }
        #pragma unroll
        for (int o = 32; o >= 1; o >>= 1) part += __shfl_down(part, o);

        // ---------- NLL: forward logsumexp scan, alpha replicated ----------
        float aown = tstart[jc] + e_lds[jc];
        float al[NT_];
        #pragma unroll
        for (int i = 0; i < NT_; ++i) al[i] = __shfl(aown, i);
        for (int tt = 1; tt < S_; ++tt) {
            float v[NT_];
            #pragma unroll
            for (int i = 0; i < NT_; ++i) v[i] = al[i] + tc[i];
            float mx = max20(v);
            float ex[NT_];
            #pragma unroll
            for (int i = 0; i < NT_; ++i) ex[i] = __builtin_amdgcn_exp2f((v[i] - mx) * LOG2E_);
            float sm = sum20(ex);
            float anew = mx + __builtin_amdgcn_logf(sm) * LN2_ + e_lds[tt * NT_ + jc];
            bool m = ((tt < 64 ? (mlo >> tt) : (mhi >> (tt - 64))) & 1ull) != 0;
            aown = m ? anew : aown;
            #pragma unroll
            for (int i = 0; i < NT_; ++i) al[i] = __shfl(aown, i);
        }
        // logz (alpha fully replicated — no cross-lane reduce needed)
        float f[NT_];
        #pragma unroll
        for (int i = 0; i < NT_; ++i) f[i] = al[i] + tend[i];
        float mx2 = max20(f);
        float ex2[NT_];
        #pragma unroll
        for (int i = 0; i < NT_; ++i) ex2[i] = __builtin_amdgcn_exp2f((f[i] - mx2) * LOG2E_);
        float logz = mx2 + __builtin_amdgcn_logf(sum20(ex2)) * LN2_;
        if (ln == 0) {
            int cnt = __popcll(mlo) + __popcll(mhi);
            float num = part + tend[tags[(cnt - 1) * B_ + b]];
            nll[b] = logz - num;
        }
    } else {
        // ---------- Viterbi: forward with backpointers, score replicated ----
        float sown = tstart[jc] + e_lds[jc];
        float sc[NT_];
        #pragma unroll
        for (int i = 0; i < NT_; ++i) sc[i] = __shfl(sown, i);
        for (int tt = 1; tt < S_; ++tt) {
            float best = sc[0] + tc[0];
            int bi = 0;
            #pragma unroll
            for (int i = 1; i < NT_; ++i) {    // strict > keeps FIRST max (jnp.argmax)
                float vv = sc[i] + tc[i];
                if (vv > best) { best = vv; bi = i; }
            }
            bool m = ((tt < 64 ? (mlo >> tt) : (mhi >> (tt - 64))) & 1ull) != 0;
            float nxt = best + e_lds[tt * NT_ + jc];
            sown = m ? nxt : sown;
            if (act) bp_lds[(tt - 1) * NT_ + ln] = m ? bi : ln;
            #pragma unroll
            for (int i = 0; i < NT_; ++i) sc[i] = __shfl(sown, i);
        }
        if (ln == 0) {
            float best = sc[0] + tend[0];
            int bt = 0;
            for (int i = 1; i < NT_; ++i) {
                float vv = sc[i] + tend[i];
                if (vv > best) { best = vv; bt = i; }
            }
            int tag = bt;
            for (int tt = S_ - 1; tt >= 1; --tt) {
                out[tt * B_ + b] = (float)tag;
                tag = bp_lds[(tt - 1) * NT_ + tag];
            }
            out[b] = (float)tag;
        }
    }
}

// ---------------- K7: final loss reduce ------------------------------------
__global__ void k_loss(const float* __restrict__ nll, float* __restrict__ out) {
    float v = nll[threadIdx.x];
    #pragma unroll
    for (int o = 32; o >= 1; o >>= 1) v += __shfl_down(v, o);
    if (threadIdx.x == 0) out[S_ * B_] = v;
}

extern "C" void kernel_launch(void* const* d_in, const int* in_sizes, int n_in,
                              void* d_out, int out_size, void* d_ws, size_t ws_size,
                              hipStream_t stream) {
    (void)in_sizes; (void)n_in; (void)out_size; (void)ws_size;
    const int*   words     = (const int*)d_in[0];
    const int*   chars     = (const int*)d_in[1];
    const int*   tags      = (const int*)d_in[2];
    const float* word_emb  = (const float*)d_in[3];
    const float* char_emb  = (const float*)d_in[4];
    const float* ccw       = (const float*)d_in[5];
    const float* ccb       = (const float*)d_in[6];
    const float* lin_w     = (const float*)d_in[7];
    const float* lin_b     = (const float*)d_in[8];
    const float* conv_w    = (const float*)d_in[9];
    const float* conv_b    = (const float*)d_in[10];
    const float* fc_w      = (const float*)d_in[11];
    const float* fc_b      = (const float*)d_in[12];
    const float* crf_start = (const float*)d_in[13];
    const float* crf_end   = (const float*)d_in[14];
    const float* crf_trans = (const float*)d_in[15];

    float* ws   = (float*)d_ws;
    float* wf   = ws + WF_OFF;
    float* em   = ws + EM_OFF;
    float* nll  = ws + NLL_OFF;
    ushort_t* hi0 = (ushort_t*)(ws + HI0_OFF);
    ushort_t* lo0 = (ushort_t*)(ws + LO0_OFF);
    ushort_t* hi1 = (ushort_t*)(ws + HI1_OFF);
    ushort_t* lo1 = (ushort_t*)(ws + LO1_OFF);
    ushort_t* whi = (ushort_t*)(ws + WHI_OFF);
    ushort_t* wlo = (ushort_t*)(ws + WLO_OFF);
    float* out  = (float*)d_out;

    k_word_gather<<<S_ * B_, 128, 0, stream>>>(words, word_emb, wf);
    k_char_cnn<<<B_ * S_, 128, 0, stream>>>(chars, char_emb, ccw, ccb, wf);
    k_split_w<<<18432, 256, 0, stream>>>(conv_w, whi, wlo);
    k_zero_pad<<<dim3(64, 4), 256, 0, stream>>>(hi0, lo0, hi1, lo1);
    k_linear<<<dim3(128, 8), 256, 0, stream>>>(wf, lin_w, lin_b, hi0, lo0);

    k_conv_gemm<<<dim3(8, 64), 256, 0, stream>>>(whi,            wlo,            hi0, lo0, conv_b,        hi1, lo1);
    k_conv_gemm<<<dim3(8, 64), 256, 0, stream>>>(whi + WLAYER,   wlo + WLAYER,   hi1, lo1, conv_b + 1024, hi0, lo0);
    k_conv_gemm<<<dim3(8, 64), 256, 0, stream>>>(whi + 2*WLAYER, wlo + 2*WLAYER, hi0, lo0, conv_b + 2048, hi1, lo1);

    k_emis2<<<B_, 256, 0, stream>>>(hi1, lo1, fc_w, fc_b, em);
    k_crf<<<B_, 128, 0, stream>>>(em, words, tags, crf_start, crf_end, crf_trans, nll, out);
    k_loss<<<1, 64, 0, stream>>>(nll, out);
}

// Round 5
// 432.568 us; speedup vs baseline: 6.0830x; 1.1964x over previous
//
#include <hip/hip_runtime.h>
#include <math.h>

typedef unsigned short ushort_t;
typedef short bf16x8 __attribute__((ext_vector_type(8)));
typedef float f32x4 __attribute__((ext_vector_type(4)));
typedef unsigned short u16x8 __attribute__((ext_vector_type(8)));

#define S_ 128
#define B_ 64
#define W_ 16
#define CE_ 30
#define FN_ 4
#define WE_ 300
#define FEAT_ 420
#define C_ 512
#define NT_ 20

#define LOG2E_ 1.44269504088896340736f
#define LN2_   0.69314718055994530942f

// ---- workspace layout (float units) ----
#define WF_OFF   0                       // 3,440,640 floats
#define EM_OFF   3440640                 // 163,840
#define NLL_OFF  3604480                 // 64
#define HI0_OFF  3604608                 // each h buffer: 64*130*512 bf16 = 2,129,920 floats
#define HBUF_F   2129920
#define LO0_OFF  (HI0_OFF + HBUF_F)
#define HI1_OFF  (LO0_OFF + HBUF_F)
#define LO1_OFF  (HI1_OFF + HBUF_F)
#define WHI_OFF  (LO1_OFF + HBUF_F)      // 3*1024*1536 bf16 = 2,359,296 floats
#define WSP_F    2359296
#define WLO_OFF  (WHI_OFF + WSP_F)
#define WLAYER   (1024*1536)             // ushort elems per layer

__device__ __forceinline__ float b2f(ushort_t h) {
    unsigned u = ((unsigned)h) << 16;
    float f; __builtin_memcpy(&f, &u, 4); return f;
}
__device__ __forceinline__ ushort_t f2b(float f) {   // round-to-nearest-even
    unsigned u; __builtin_memcpy(&u, &f, 4);
    unsigned r = (u + 0x7FFFu + ((u >> 16) & 1u)) >> 16;
    return (ushort_t)r;
}
__device__ __forceinline__ void gload16(const void* g, void* l) {
    __builtin_amdgcn_global_load_lds((const __attribute__((address_space(1))) void*)g,
                                     (__attribute__((address_space(3))) void*)l,
                                     16, 0, 0);
}
__device__ __forceinline__ float max20(const float* v) {
    float m0=fmaxf(v[0],v[1]),  m1=fmaxf(v[2],v[3]),  m2=fmaxf(v[4],v[5]),
          m3=fmaxf(v[6],v[7]),  m4=fmaxf(v[8],v[9]),  m5=fmaxf(v[10],v[11]),
          m6=fmaxf(v[12],v[13]),m7=fmaxf(v[14],v[15]),m8=fmaxf(v[16],v[17]),
          m9=fmaxf(v[18],v[19]);
    return fmaxf(fmaxf(fmaxf(fmaxf(m0,m1),fmaxf(m2,m3)),
                       fmaxf(fmaxf(m4,m5),fmaxf(m6,m7))), fmaxf(m8,m9));
}
__device__ __forceinline__ float sum20(const float* v) {
    float s0=v[0]+v[1],  s1=v[2]+v[3],  s2=v[4]+v[5],  s3=v[6]+v[7],
          s4=v[8]+v[9],  s5=v[10]+v[11],s6=v[12]+v[13],s7=v[14]+v[15],
          s8=v[16]+v[17],s9=v[18]+v[19];
    return (((s0+s1)+(s2+s3))+((s4+s5)+(s6+s7)))+(s8+s9);
}

// ---------------- K1a: word embedding gather -> wf[:, :300] ----------------
__global__ void k_word_gather(const int* __restrict__ words,
                              const float* __restrict__ word_emb,
                              float* __restrict__ wf) {
    int n = blockIdx.x;                  // n = s*B + b
    int wid = words[n];
    int t = threadIdx.x;
    if (t < WE_ / 4) {
        const float4* src = (const float4*)(word_emb + (size_t)wid * WE_);
        float4* dst = (float4*)(wf + (size_t)n * FEAT_);
        dst[t] = src[t];
    }
}

// ---------------- K1b: char depthwise CNN + maxpool -> wf[:, 300:420] ------
__global__ void k_char_cnn(const int* __restrict__ chars,
                           const float* __restrict__ char_emb,
                           const float* __restrict__ cw,
                           const float* __restrict__ cb,
                           float* __restrict__ wf) {
    int n = blockIdx.x;                  // n = b*S + s
    int b = n >> 7;
    int s = n & 127;
    __shared__ int cidx[W_];
    int t = threadIdx.x;
    if (t < W_) cidx[t] = chars[n * W_ + t];
    __syncthreads();
    if (t < CE_ * FN_) {
        int g = t >> 2;
        float w0 = cw[t*3+0], w1 = cw[t*3+1], w2 = cw[t*3+2];
        float x[W_];
        #pragma unroll
        for (int j = 0; j < W_; ++j) x[j] = char_emb[cidx[j] * CE_ + g];
        float m = -INFINITY;
        #pragma unroll
        for (int j = 0; j < W_ - 2; ++j) {
            float v = x[j]*w0 + x[j+1]*w1 + x[j+2]*w2;
            m = fmaxf(m, v);
        }
        wf[(size_t)(s * B_ + b) * FEAT_ + WE_ + t] = m + cb[t];
    }
}

// ---------------- split conv weights into bf16 hi/lo, k' = kr*512+ci -------
__global__ void k_split_w(const float* __restrict__ conv_w,
                          ushort_t* __restrict__ Whi, ushort_t* __restrict__ Wlo) {
    size_t i = (size_t)blockIdx.x * 256 + threadIdx.x;   // 3*1024*1536 total
    int ci = (int)(i & 511);
    int kr = (int)((i >> 9) % 3);
    size_t lo_ = i / 1536;                               // l*1024 + o
    float v = conv_w[lo_ * 1536 + (size_t)ci * 3 + kr];
    ushort_t hi = f2b(v);
    ushort_t lo = f2b(v - b2f(hi));
    Whi[i] = hi; Wlo[i] = lo;
}

// ---------------- zero the pad rows (s'=0, s'=129) of h buffers ------------
__global__ void k_zero_pad(ushort_t* b0, ushort_t* b1, ushort_t* b2, ushort_t* b3) {
    ushort_t* bufs[4] = {b0, b1, b2, b3};
    ushort_t* buf = bufs[blockIdx.y];
    int b = blockIdx.x;
    int t = threadIdx.x;                 // 256 threads; row = 512 bf16 = 256 uints
    unsigned* r0 = (unsigned*)(buf + ((size_t)b * 130 + 0) * 512);
    unsigned* r1 = (unsigned*)(buf + ((size_t)b * 130 + 129) * 512);
    r0[t] = 0u; r1[t] = 0u;
}

// ---------------- K2: linear 420 -> 512, out h (b,s,c) bf16 hi/lo ----------
__global__ __launch_bounds__(256) void k_linear(const float* __restrict__ wf,
                                                const float* __restrict__ lin_w,
                                                const float* __restrict__ lin_b,
                                                ushort_t* __restrict__ hhi,
                                                ushort_t* __restrict__ hlo) {
    __shared__ float As[16][68];
    __shared__ float Bs[64][17];
    int n0 = blockIdx.x * 64;            // n = b*S + s
    int c0 = blockIdx.y * 64;
    int t = threadIdx.x;
    int cc = (t & 15) * 4;
    int nn = (t >> 4) * 4;
    float acc[4][4] = {};
    for (int k0 = 0; k0 < FEAT_; k0 += 16) {
        {
            int kk = t >> 4;
            int c4 = (t & 15) * 4;
            float4 v = make_float4(0.f, 0.f, 0.f, 0.f);
            if (k0 + kk < FEAT_)
                v = *(const float4*)(lin_w + (size_t)(k0 + kk) * C_ + c0 + c4);
            *(float4*)&As[kk][c4] = v;
        }
        {
            int nl = t >> 2;
            int fq = (t & 3) * 4;
            int n = n0 + nl;
            int row = (n & 127) * B_ + (n >> 7);
            float4 v = make_float4(0.f, 0.f, 0.f, 0.f);
            if (k0 + fq < FEAT_)
                v = *(const float4*)(wf + (size_t)row * FEAT_ + k0 + fq);
            Bs[nl][fq+0] = v.x; Bs[nl][fq+1] = v.y;
            Bs[nl][fq+2] = v.z; Bs[nl][fq+3] = v.w;
        }
        __syncthreads();
        #pragma unroll
        for (int kk = 0; kk < 16; ++kk) {
            float4 a4 = *(float4*)&As[kk][cc];
            float b0 = Bs[nn+0][kk], b1 = Bs[nn+1][kk];
            float b2 = Bs[nn+2][kk], b3 = Bs[nn+3][kk];
            acc[0][0] += a4.x*b0; acc[0][1] += a4.x*b1; acc[0][2] += a4.x*b2; acc[0][3] += a4.x*b3;
            acc[1][0] += a4.y*b0; acc[1][1] += a4.y*b1; acc[1][2] += a4.y*b2; acc[1][3] += a4.y*b3;
            acc[2][0] += a4.z*b0; acc[2][1] += a4.z*b1; acc[2][2] += a4.z*b2; acc[2][3] += a4.z*b3;
            acc[3][0] += a4.w*b0; acc[3][1] += a4.w*b1; acc[3][2] += a4.w*b2; acc[3][3] += a4.w*b3;
        }
        __syncthreads();
    }
    int n = n0 + nn;
    int b = n >> 7, s = n & 127;
    float4 bb = *(const float4*)(lin_b + c0 + cc);
    #pragma unroll
    for (int j = 0; j < 4; ++j) {
        float x0 = acc[0][j] + bb.x;
        float x1 = acc[1][j] + bb.y;
        float x2 = acc[2][j] + bb.z;
        float x3 = acc[3][j] + bb.w;
        ushort4 h4, l4;
        h4.x = f2b(x0); l4.x = f2b(x0 - b2f(h4.x));
        h4.y = f2b(x1); l4.y = f2b(x1 - b2f(h4.y));
        h4.z = f2b(x2); l4.z = f2b(x2 - b2f(h4.z));
        h4.w = f2b(x3); l4.w = f2b(x3 - b2f(h4.w));
        size_t dst = ((size_t)b * 130 + s + j + 1) * 512 + c0 + cc;
        *(ushort4*)(hhi + dst) = h4;
        *(ushort4*)(hlo + dst) = l4;
    }
}

// ---------------- K3: GLU conv layer as split-bf16 MFMA GEMM ---------------
// Fused 3-product staging: per (kr,ci0) stage Ah,Al,Bh,Bl (32KB) once, then
// 48 MFMA (Ah*Bh + Ah*Bl + Al*Bh) per barrier pair.  Grid: 1D 512,
// co = bid&7, b = bid>>3  ->  each XCD keeps ONE 768KB weight panel L2-hot.
__global__ __launch_bounds__(256) void k_conv_gemm(
    const ushort_t* __restrict__ Wh, const ushort_t* __restrict__ Wl,
    const ushort_t* __restrict__ Hh, const ushort_t* __restrict__ Hl,
    const float* __restrict__ cb,          // conv_b + l*1024
    ushort_t* __restrict__ Oh, ushort_t* __restrict__ Ol)
{
    __shared__ float g_lds[128 * 68];      // 34816 B; tiles alias the first 32 KB
    short* Ah = (short*)g_lds;             // [128][32] bf16
    short* Al = Ah + 4096;
    short* Bh = Al + 4096;
    short* Bl = Bh + 4096;

    const int bid  = blockIdx.x;
    const int co0  = (bid & 7) << 6;       // 64 output channels per block
    const int b    = bid >> 3;
    const int t    = threadIdx.x;
    const int w    = t >> 6;               // wave 0..3
    const int lane = t & 63;
    const int wr   = w >> 1;               // 0: a-rows, 1: g-rows
    const int wc   = w & 1;                // s half

    const int srow0 = (w << 5) + (lane >> 2);
    const int srow1 = srow0 + 16;
    const int j0 = (lane & 3) ^ ((srow0 >> 1) & 3);
    const int j1 = (lane & 3) ^ ((srow1 >> 1) & 3);
    const int coA0 = (srow0 < 64) ? (co0 + srow0) : (512 + co0 + srow0 - 64);
    const int coA1 = (srow1 < 64) ? (co0 + srow1) : (512 + co0 + srow1 - 64);
    const size_t aoff0 = (size_t)coA0 * 1536 + j0 * 8;
    const size_t aoff1 = (size_t)coA1 * 1536 + j1 * 8;
    const size_t hoff0 = ((size_t)b * 130 + srow0) * 512 + j0 * 8;
    const size_t hoff1 = ((size_t)b * 130 + srow1) * 512 + j1 * 8;
    const int wofs = w << 10;              // wave's 32-row slab (shorts)

    const int lr = lane & 15, kg = lane >> 4;
    int aro[4], bro[4];
    #pragma unroll
    for (int m = 0; m < 4; ++m) { int r = (wr << 6) + (m << 4) + lr; aro[m] = (r << 5) + ((kg ^ ((r >> 1) & 3)) << 3); }
    #pragma unroll
    for (int n = 0; n < 4; ++n) { int r = (wc << 6) + (n << 4) + lr; bro[n] = (r << 5) + ((kg ^ ((r >> 1) & 3)) << 3); }

    f32x4 acc[4][4];
    #pragma unroll
    for (int m = 0; m < 4; ++m)
        #pragma unroll
        for (int n = 0; n < 4; ++n) acc[m][n] = (f32x4){0.f, 0.f, 0.f, 0.f};

    for (int kr = 0; kr < 3; ++kr) {
        const size_t hk0 = hoff0 + (size_t)kr * 512;   // row s+kr in padded layout
        const size_t hk1 = hoff1 + (size_t)kr * 512;
        for (int ci0 = 0; ci0 < 512; ci0 += 32) {
            const int kb = kr * 512 + ci0;
            gload16(Wh + aoff0 + kb, Ah + wofs);
            gload16(Wh + aoff1 + kb, Ah + wofs + 512);
            gload16(Wl + aoff0 + kb, Al + wofs);
            gload16(Wl + aoff1 + kb, Al + wofs + 512);
            gload16(Hh + hk0 + ci0, Bh + wofs);
            gload16(Hh + hk1 + ci0, Bh + wofs + 512);
            gload16(Hl + hk0 + ci0, Bl + wofs);
            gload16(Hl + hk1 + ci0, Bl + wofs + 512);
            __syncthreads();
            bf16x8 avh[4], avl[4], bvh[4], bvl[4];
            #pragma unroll
            for (int m = 0; m < 4; ++m) { avh[m] = *(const bf16x8*)(Ah + aro[m]);
                                          avl[m] = *(const bf16x8*)(Al + aro[m]); }
            #pragma unroll
            for (int n = 0; n < 4; ++n) { bvh[n] = *(const bf16x8*)(Bh + bro[n]);
                                          bvl[n] = *(const bf16x8*)(Bl + bro[n]); }
            #pragma unroll
            for (int m = 0; m < 4; ++m)
                #pragma unroll
                for (int n = 0; n < 4; ++n) {
                    acc[m][n] = __builtin_amdgcn_mfma_f32_16x16x32_bf16(avh[m], bvh[n], acc[m][n], 0, 0, 0);
                    acc[m][n] = __builtin_amdgcn_mfma_f32_16x16x32_bf16(avh[m], bvl[n], acc[m][n], 0, 0, 0);
                    acc[m][n] = __builtin_amdgcn_mfma_f32_16x16x32_bf16(avl[m], bvh[n], acc[m][n], 0, 0, 0);
                }
            __syncthreads();
        }
    }

    // ---- fused GLU epilogue: g-waves hand their acc to a-waves via LDS ----
    const float rs = 0.70710678118654752f;
    if (wr == 1) {
        #pragma unroll
        for (int m = 0; m < 4; ++m) {
            const int co_l = (m << 4) + (kg << 2);
            float4 bg = *(const float4*)(cb + 512 + co0 + co_l);
            #pragma unroll
            for (int n = 0; n < 4; ++n) {
                const int s_l = (wc << 6) + (n << 4) + lr;
                float4 gv;
                gv.x = acc[m][n][0] + bg.x;
                gv.y = acc[m][n][1] + bg.y;
                gv.z = acc[m][n][2] + bg.z;
                gv.w = acc[m][n][3] + bg.w;
                *(float4*)&g_lds[s_l * 68 + co_l] = gv;
            }
        }
    }
    __syncthreads();
    if (wr == 0) {
        #pragma unroll
        for (int m = 0; m < 4; ++m) {
            const int co_l = (m << 4) + (kg << 2);
            float4 ba = *(const float4*)(cb + co0 + co_l);
            #pragma unroll
            for (int n = 0; n < 4; ++n) {
                const int s_l = (wc << 6) + (n << 4) + lr;
                float4 gv = *(const float4*)&g_lds[s_l * 68 + co_l];
                size_t dst = ((size_t)b * 130 + s_l + 1) * 512 + co0 + co_l;
                ushort4 rh = *(const ushort4*)(Hh + dst);
                ushort4 rl = *(const ushort4*)(Hl + dst);
                float a0 = acc[m][n][0] + ba.x, g0 = gv.x;
                float a1 = acc[m][n][1] + ba.y, g1 = gv.y;
                float a2 = acc[m][n][2] + ba.z, g2 = gv.z;
                float a3 = acc[m][n][3] + ba.w, g3 = gv.w;
                float o0 = (a0 / (1.f + expf(-g0)) + (b2f(rh.x) + b2f(rl.x))) * rs;
                float o1 = (a1 / (1.f + expf(-g1)) + (b2f(rh.y) + b2f(rl.y))) * rs;
                float o2 = (a2 / (1.f + expf(-g2)) + (b2f(rh.z) + b2f(rl.z))) * rs;
                float o3 = (a3 / (1.f + expf(-g3)) + (b2f(rh.w) + b2f(rl.w))) * rs;
                ushort4 h4, l4;
                h4.x = f2b(o0); l4.x = f2b(o0 - b2f(h4.x));
                h4.y = f2b(o1); l4.y = f2b(o1 - b2f(h4.y));
                h4.z = f2b(o2); l4.z = f2b(o2 - b2f(h4.z));
                h4.w = f2b(o3); l4.w = f2b(o3 - b2f(h4.w));
                *(ushort4*)(Oh + dst) = h4;
                *(ushort4*)(Ol + dst) = l4;
            }
        }
    }
}

// ---------------- K4: emissions 512 -> 20 (h in (b,s,c) bf16 hi/lo) --------
__global__ __launch_bounds__(256) void k_emis2(const ushort_t* __restrict__ hhi,
                                               const ushort_t* __restrict__ hlo,
                                               const float* __restrict__ fc_w,
                                               const float* __restrict__ fc_b,
                                               float* __restrict__ emis) {
    __shared__ float hsE[128][33];
    __shared__ float wsE[32][20];
    int b = blockIdx.x, t = threadIdx.x;
    int tg = t >> 7, s = t & 127;
    float acc[10] = {};
    for (int c0 = 0; c0 < C_; c0 += 32) {
        #pragma unroll
        for (int i = 0; i < 2; ++i) {
            int flat = t + i * 256;
            int row = flat >> 2, ch = (flat & 3) * 8;
            size_t src = ((size_t)b * 130 + row + 1) * 512 + c0 + ch;
            u16x8 vh = *(const u16x8*)(hhi + src);
            u16x8 vl = *(const u16x8*)(hlo + src);
            #pragma unroll
            for (int k = 0; k < 8; ++k) hsE[row][ch + k] = b2f(vh[k]) + b2f(vl[k]);
        }
        for (int idx = t; idx < 32 * NT_; idx += 256) {
            int kk = idx / NT_, tt = idx - kk * NT_;
            wsE[kk][tt] = fc_w[(size_t)(c0 + kk) * NT_ + tt];
        }
        __syncthreads();
        #pragma unroll
        for (int kk = 0; kk < 32; ++kk) {
            float hv = hsE[s][kk];
            #pragma unroll
            for (int j = 0; j < 10; ++j) acc[j] += hv * wsE[kk][tg * 10 + j];
        }
        __syncthreads();
    }
    #pragma unroll
    for (int j = 0; j < 10; ++j)
        emis[((size_t)s * B_ + b) * NT_ + tg * 10 + j] = acc[j] + fc_b[tg * 10 + j];
}

// ---------------- K5: fused CRF NLL (wave 0) + Viterbi (wave 1) ------------
__global__ __launch_bounds__(128) void k_crf(const float* __restrict__ emis,
                                             const int* __restrict__ words,
                                             const int* __restrict__ tags,
                                             const float* __restrict__ tstart,
                                             const float* __restrict__ tend,
                                             const float* __restrict__ ttrans,
                                             float* __restrict__ nll,
                                             float* __restrict__ out) {
    __shared__ float e_lds[S_ * NT_];          // 10240 B
    __shared__ int   bp_lds[(S_ - 1) * NT_];   // 10160 B
    const int b = blockIdx.x;
    const int t = threadIdx.x;

    for (int idx = t; idx < S_ * NT_; idx += 128) {
        int tt = idx / NT_, j = idx - tt * NT_;
        e_lds[idx] = emis[((size_t)tt * B_ + b) * NT_ + j];
    }
    __syncthreads();

    const int ln = t & 63;
    unsigned long long mlo = __ballot(words[ln * B_ + b] != 0);
    unsigned long long mhi = __ballot(words[(64 + ln) * B_ + b] != 0);
    const bool act = ln < NT_;
    const int jc = act ? ln : 0;
    float tc[NT_];
    #pragma unroll
    for (int i = 0; i < NT_; ++i) tc[i] = act ? ttrans[i * NT_ + ln] : 0.f;

    if (t < 64) {
        // ---------- NLL: numerator ----------
        float part = 0.f;
        for (int tt = ln; tt < S_; tt += 64) {
            int tgc = tags[tt * B_ + b];
            bool m = ((tt < 64 ? (mlo >> tt) : (mhi >> (tt - 64))) & 1ull) != 0;
            if (tt == 0) {
                part += tstart[tgc] + e_lds[tgc];
            } else if (m) {
                int tgp = tags[(tt - 1) * B_ + b];
                part += ttrans[tgp * NT_ + tgc] + e_lds[tt * NT_ + tgc];
            }
        }
        #pragma unroll
        for (int o = 32; o >= 1; o >>= 1) part += __shfl_down(part, o);

        // ---------- NLL: forward logsumexp scan, alpha replicated ----------
        float aown = tstart[jc] + e_lds[jc];
        float al[NT_];
        #pragma unroll
        for (int i = 0; i < NT_; ++i) al[i] = __shfl(aown, i);
        for (int tt = 1; tt < S_; ++tt) {
            float v[NT_];
            #pragma unroll
            for (int i = 0; i < NT_; ++i) v[i] = al[i] + tc[i];
            float mx = max20(v);
            float ex[NT_];
            #pragma unroll
            for (int i = 0; i < NT_; ++i) ex[i] = __builtin_amdgcn_exp2f((v[i] - mx) * LOG2E_);
            float sm = sum20(ex);
            float anew = mx + __builtin_amdgcn_logf(sm) * LN2_ + e_lds[tt * NT_ + jc];
            bool m = ((tt < 64 ? (mlo >> tt) : (mhi >> (tt - 64))) & 1ull) != 0;
            aown = m ? anew : aown;
            #pragma unroll
            for (int i = 0; i < NT_; ++i) al[i] = __shfl(aown, i);
        }
        // logz (alpha fully replicated — no cross-lane reduce needed)
        float f[NT_];
        #pragma unroll
        for (int i = 0; i < NT_; ++i) f[i] = al[i] + tend[i];
        float mx2 = max20(f);
        float ex2[NT_];
        #pragma unroll
        for (int i = 0; i < NT_; ++i) ex2[i] = __builtin_amdgcn_exp2f((f[i] - mx2) * LOG2E_);
        float logz = mx2 + __builtin_amdgcn_logf(sum20(ex2)) * LN2_;
        if (ln == 0) {
            int cnt = __popcll(mlo) + __popcll(mhi);
            float num = part + tend[tags[(cnt - 1) * B_ + b]];
            nll[b] = logz - num;
        }
    } else {
        // ---------- Viterbi: forward with backpointers, score replicated ----
        float sown = tstart[jc] + e_lds[jc];
        float sc[NT_];
        #pragma unroll
        for (int i = 0; i < NT_; ++i) sc[i] = __shfl(sown, i);
        for (int tt = 1; tt < S_; ++tt) {
            float best = sc[0] + tc[0];
            int bi = 0;
            #pragma unroll
            for (int i = 1; i < NT_; ++i) {    // strict > keeps FIRST max (jnp.argmax)
                float vv = sc[i] + tc[i];
                if (vv > best) { best = vv; bi = i; }
            }
            bool m = ((tt < 64 ? (mlo >> tt) : (mhi >> (tt - 64))) & 1ull) != 0;
            float nxt = best + e_lds[tt * NT_ + jc];
            sown = m ? nxt : sown;
            if (act) bp_lds[(tt - 1) * NT_ + ln] = m ? bi : ln;
            #pragma unroll
            for (int i = 0; i < NT_; ++i) sc[i] = __shfl(sown, i);
        }
        if (ln == 0) {
            float best = sc[0] + tend[0];
            int bt = 0;
            for (int i = 1; i < NT_; ++i) {
                float vv = sc[i] + tend[i];
                if (vv > best) { best = vv; bt = i; }
            }
            int tag = bt;
            for (int tt = S_ - 1; tt >= 1; --tt) {
                out[tt * B_ + b] = (float)tag;
                tag = bp_lds[(tt - 1) * NT_ + tag];
            }
            out[b] = (float)tag;
        }
    }
}

// ---------------- K7: final loss reduce ------------------------------------
__global__ void k_loss(const float* __restrict__ nll, float* __restrict__ out) {
    float v = nll[threadIdx.x];
    #pragma unroll
    for (int o = 32; o >= 1; o >>= 1) v += __shfl_down(v, o);
    if (threadIdx.x == 0) out[S_ * B_] = v;
}

extern "C" void kernel_launch(void* const* d_in, const int* in_sizes, int n_in,
                              void* d_out, int out_size, void* d_ws, size_t ws_size,
                              hipStream_t stream) {
    (void)in_sizes; (void)n_in; (void)out_size; (void)ws_size;
    const int*   words     = (const int*)d_in[0];
    const int*   chars     = (const int*)d_in[1];
    const int*   tags      = (const int*)d_in[2];
    const float* word_emb  = (const float*)d_in[3];
    const float* char_emb  = (const float*)d_in[4];
    const float* ccw       = (const float*)d_in[5];
    const float* ccb       = (const float*)d_in[6];
    const float* lin_w     = (const float*)d_in[7];
    const float* lin_b     = (const float*)d_in[8];
    const float* conv_w    = (const float*)d_in[9];
    const float* conv_b    = (const float*)d_in[10];
    const float* fc_w      = (const float*)d_in[11];
    const float* fc_b      = (const float*)d_in[12];
    const float* crf_start = (const float*)d_in[13];
    const float* crf_end   = (const float*)d_in[14];
    const float* crf_trans = (const float*)d_in[15];

    float* ws   = (float*)d_ws;
    float* wf   = ws + WF_OFF;
    float* em   = ws + EM_OFF;
    float* nll  = ws + NLL_OFF;
    ushort_t* hi0 = (ushort_t*)(ws + HI0_OFF);
    ushort_t* lo0 = (ushort_t*)(ws + LO0_OFF);
    ushort_t* hi1 = (ushort_t*)(ws + HI1_OFF);
    ushort_t* lo1 = (ushort_t*)(ws + LO1_OFF);
    ushort_t* whi = (ushort_t*)(ws + WHI_OFF);
    ushort_t* wlo = (ushort_t*)(ws + WLO_OFF);
    float* out  = (float*)d_out;

    k_word_gather<<<S_ * B_, 128, 0, stream>>>(words, word_emb, wf);
    k_char_cnn<<<B_ * S_, 128, 0, stream>>>(chars, char_emb, ccw, ccb, wf);
    k_split_w<<<18432, 256, 0, stream>>>(conv_w, whi, wlo);
    k_zero_pad<<<dim3(64, 4), 256, 0, stream>>>(hi0, lo0, hi1, lo1);
    k_linear<<<dim3(128, 8), 256, 0, stream>>>(wf, lin_w, lin_b, hi0, lo0);

    k_conv_gemm<<<512, 256, 0, stream>>>(whi,            wlo,            hi0, lo0, conv_b,        hi1, lo1);
    k_conv_gemm<<<512, 256, 0, stream>>>(whi + WLAYER,   wlo + WLAYER,   hi1, lo1, conv_b + 1024, hi0, lo0);
    k_conv_gemm<<<512, 256, 0, stream>>>(whi + 2*WLAYER, wlo + 2*WLAYER, hi0, lo0, conv_b + 2048, hi1, lo1);

    k_emis2<<<B_, 256, 0, stream>>>(hi1, lo1, fc_w, fc_b, em);
    k_crf<<<B_, 128, 0, stream>>>(em, words, tags, crf_start, crf_end, crf_trans, nll, out);
    k_loss<<<1, 64, 0, stream>>>(nll, out);
}

// Round 7
// 254.085 us; speedup vs baseline: 10.3561x; 1.7025x over previous
//
#include <hip/hip_runtime.h>
#include <math.h>

typedef unsigned short ushort_t;
typedef short bf16x8 __attribute__((ext_vector_type(8)));
typedef float f32x4 __attribute__((ext_vector_type(4)));
typedef unsigned short u16x8 __attribute__((ext_vector_type(8)));

#define S_ 128
#define B_ 64
#define W_ 16
#define CE_ 30
#define FN_ 4
#define WE_ 300
#define FEAT_ 420
#define C_ 512
#define NT_ 20
#define KL_ 448          // padded K for the 420->512 linear

#define LOG2E_ 1.44269504088896340736f
#define LN2_   0.69314718055994530942f

// ---- workspace layout (float units) ----
#define WF_OFF   0                       // 3,440,640 floats
#define EM_OFF   3440640                 // 163,840
#define NLL_OFF  3604480                 // 64
#define H0_OFF   3604608                 // each h buffer: 64*130*512 bf16 = 2,129,920 floats
#define HBUF_F   2129920
#define H1_OFF   (H0_OFF + HBUF_F)
#define WS_OFF   (H1_OFF + HBUF_F)       // conv w bf16: 3*1024*1536 = 2,359,296 floats
#define WSP_F    2359296
#define LW_OFF   (WS_OFF + WSP_F)        // lin_w bf16: 512*448 = 114,688 floats
#define FS_OFF   (LW_OFF + 114688)       // wf bf16: 8192*448 = 1,835,008 floats
#define WLAYER   (1024*1536)             // ushort elems per layer

__device__ __forceinline__ float b2f(ushort_t h) {
    unsigned u = ((unsigned)h) << 16;
    float f; __builtin_memcpy(&f, &u, 4); return f;
}
__device__ __forceinline__ ushort_t f2b(float f) {   // round-to-nearest-even
    unsigned u; __builtin_memcpy(&u, &f, 4);
    unsigned r = (u + 0x7FFFu + ((u >> 16) & 1u)) >> 16;
    return (ushort_t)r;
}
__device__ __forceinline__ void gload16(const void* g, void* l) {
    __builtin_amdgcn_global_load_lds((const __attribute__((address_space(1))) void*)g,
                                     (__attribute__((address_space(3))) void*)l,
                                     16, 0, 0);
}
__device__ __forceinline__ float max20(const float* v) {
    float m0=fmaxf(v[0],v[1]),  m1=fmaxf(v[2],v[3]),  m2=fmaxf(v[4],v[5]),
          m3=fmaxf(v[6],v[7]),  m4=fmaxf(v[8],v[9]),  m5=fmaxf(v[10],v[11]),
          m6=fmaxf(v[12],v[13]),m7=fmaxf(v[14],v[15]),m8=fmaxf(v[16],v[17]),
          m9=fmaxf(v[18],v[19]);
    return fmaxf(fmaxf(fmaxf(fmaxf(m0,m1),fmaxf(m2,m3)),
                       fmaxf(fmaxf(m4,m5),fmaxf(m6,m7))), fmaxf(m8,m9));
}
__device__ __forceinline__ float sum20(const float* v) {
    float s0=v[0]+v[1],  s1=v[2]+v[3],  s2=v[4]+v[5],  s3=v[6]+v[7],
          s4=v[8]+v[9],  s5=v[10]+v[11],s6=v[12]+v[13],s7=v[14]+v[15],
          s8=v[16]+v[17],s9=v[18]+v[19];
    return (((s0+s1)+(s2+s3))+((s4+s5)+(s6+s7)))+(s8+s9);
}

// ---------------- K1a: word embedding gather -> wf[:, :300] ----------------
__global__ void k_word_gather(const int* __restrict__ words,
                              const float* __restrict__ word_emb,
                              float* __restrict__ wf) {
    int n = blockIdx.x;                  // n = s*B + b
    int wid = words[n];
    int t = threadIdx.x;
    if (t < WE_ / 4) {
        const float4* src = (const float4*)(word_emb + (size_t)wid * WE_);
        float4* dst = (float4*)(wf + (size_t)n * FEAT_);
        dst[t] = src[t];
    }
}

// ---------------- K1b: char depthwise CNN + maxpool -> wf[:, 300:420] ------
__global__ void k_char_cnn(const int* __restrict__ chars,
                           const float* __restrict__ char_emb,
                           const float* __restrict__ cw,
                           const float* __restrict__ cb,
                           float* __restrict__ wf) {
    int n = blockIdx.x;                  // n = b*S + s
    int b = n >> 7;
    int s = n & 127;
    __shared__ int cidx[W_];
    int t = threadIdx.x;
    if (t < W_) cidx[t] = chars[n * W_ + t];
    __syncthreads();
    if (t < CE_ * FN_) {
        int g = t >> 2;
        float w0 = cw[t*3+0], w1 = cw[t*3+1], w2 = cw[t*3+2];
        float x[W_];
        #pragma unroll
        for (int j = 0; j < W_; ++j) x[j] = char_emb[cidx[j] * CE_ + g];
        float m = -INFINITY;
        #pragma unroll
        for (int j = 0; j < W_ - 2; ++j) {
            float v = x[j]*w0 + x[j+1]*w1 + x[j+2]*w2;
            m = fmaxf(m, v);
        }
        wf[(size_t)(s * B_ + b) * FEAT_ + WE_ + t] = m + cb[t];
    }
}

// ---------------- conv weights -> bf16, k' = kr*512+ci ---------------------
__global__ void k_split_w(const float* __restrict__ conv_w,
                          ushort_t* __restrict__ Wt) {
    size_t i = (size_t)blockIdx.x * 256 + threadIdx.x;   // 3*1024*1536 total
    int ci = (int)(i & 511);
    int kr = (int)((i >> 9) % 3);
    size_t lo_ = i / 1536;                               // l*1024 + o
    Wt[i] = f2b(conv_w[lo_ * 1536 + (size_t)ci * 3 + kr]);
}

// ---------------- lin_w -> [c=512][k=448] bf16 (transposed, padded) --------
__global__ void k_split_lw(const float* __restrict__ lin_w,
                           ushort_t* __restrict__ Lh) {
    int k = blockIdx.x;                  // 0..447
    int c = threadIdx.x;                 // 0..511
    float v = (k < FEAT_) ? lin_w[(size_t)k * C_ + c] : 0.f;
    Lh[(size_t)c * KL_ + k] = f2b(v);
}

// ---------------- wf -> [n'=b*128+s][448] bf16 -----------------------------
__global__ void k_split_wf(const float* __restrict__ wf,
                           ushort_t* __restrict__ Fh) {
    int np = blockIdx.x;                 // n' = b*128 + s
    int b = np >> 7, s = np & 127;
    const float* src = wf + (size_t)(s * B_ + b) * FEAT_;
    int t = threadIdx.x;                 // 224 threads x 2 cols
    #pragma unroll
    for (int r = 0; r < 2; ++r) {
        int k = t + r * 224;
        float v = (k < FEAT_) ? src[k] : 0.f;
        Fh[(size_t)np * KL_ + k] = f2b(v);
    }
}

// ---------------- zero the pad rows (s'=0, s'=129) of h buffers ------------
__global__ void k_zero_pad(ushort_t* b0, ushort_t* b1) {
    ushort_t* buf = blockIdx.y ? b1 : b0;
    int b = blockIdx.x;
    int t = threadIdx.x;                 // 256 threads; row = 512 bf16 = 256 uints
    unsigned* r0 = (unsigned*)(buf + ((size_t)b * 130 + 0) * 512);
    unsigned* r1 = (unsigned*)(buf + ((size_t)b * 130 + 129) * 512);
    r0[t] = 0u; r1[t] = 0u;
}

// ---------------- K2: linear 420->512 as bf16 MFMA GEMM --------------------
// M=512 c (4 panels), N=8192 n' (64 panels), K=448, BK=32. Grid 256.
__global__ __launch_bounds__(256) void k_lin_gemm(
    const ushort_t* __restrict__ Lh, const ushort_t* __restrict__ Fh,
    const float* __restrict__ lb, ushort_t* __restrict__ Oh)
{
    __shared__ short lds[8192];          // A, B tiles 4096 shorts each
    short* AhS = lds;
    short* BhS = lds + 4096;

    const int bid = blockIdx.x;
    const int c0 = (bid & 3) << 7;
    const int n0 = (bid >> 2) << 7;
    const int t = threadIdx.x;
    const int w = t >> 6;
    const int lane = t & 63;
    const int wr = w >> 1, wc = w & 1;

    const int srow0 = (w << 5) + (lane >> 2);
    const int srow1 = srow0 + 16;
    const int j0 = (lane & 3) ^ ((srow0 >> 1) & 3);
    const int j1 = (lane & 3) ^ ((srow1 >> 1) & 3);
    const size_t aoff0 = (size_t)(c0 + srow0) * KL_ + j0 * 8;
    const size_t aoff1 = (size_t)(c0 + srow1) * KL_ + j1 * 8;
    const size_t boff0 = (size_t)(n0 + srow0) * KL_ + j0 * 8;
    const size_t boff1 = (size_t)(n0 + srow1) * KL_ + j1 * 8;
    const int wofs = w << 10;

    const int lr = lane & 15, kg = lane >> 4;
    int aro[4], bro[4];
    #pragma unroll
    for (int m = 0; m < 4; ++m) { int r = (wr << 6) + (m << 4) + lr; aro[m] = (r << 5) + ((kg ^ ((r >> 1) & 3)) << 3); }
    #pragma unroll
    for (int n = 0; n < 4; ++n) { int r = (wc << 6) + (n << 4) + lr; bro[n] = (r << 5) + ((kg ^ ((r >> 1) & 3)) << 3); }

    f32x4 acc[4][4];
    #pragma unroll
    for (int m = 0; m < 4; ++m)
        #pragma unroll
        for (int n = 0; n < 4; ++n) acc[m][n] = (f32x4){0.f, 0.f, 0.f, 0.f};

    for (int k0 = 0; k0 < KL_; k0 += 32) {
        gload16(Lh + aoff0 + k0, AhS + wofs);
        gload16(Lh + aoff1 + k0, AhS + wofs + 512);
        gload16(Fh + boff0 + k0, BhS + wofs);
        gload16(Fh + boff1 + k0, BhS + wofs + 512);
        __syncthreads();
        bf16x8 avh[4], bvh[4];
        #pragma unroll
        for (int m = 0; m < 4; ++m) avh[m] = *(const bf16x8*)(AhS + aro[m]);
        #pragma unroll
        for (int n = 0; n < 4; ++n) bvh[n] = *(const bf16x8*)(BhS + bro[n]);
        #pragma unroll
        for (int m = 0; m < 4; ++m)
            #pragma unroll
            for (int n = 0; n < 4; ++n)
                acc[m][n] = __builtin_amdgcn_mfma_f32_16x16x32_bf16(avh[m], bvh[n], acc[m][n], 0, 0, 0);
        __syncthreads();
    }

    #pragma unroll
    for (int m = 0; m < 4; ++m) {
        const int c = c0 + (wr << 6) + (m << 4) + (kg << 2);
        float4 bb = *(const float4*)(lb + c);
        #pragma unroll
        for (int n = 0; n < 4; ++n) {
            const int np = n0 + (wc << 6) + (n << 4) + lr;
            const int b = np >> 7, s = np & 127;
            ushort4 h4;
            h4.x = f2b(acc[m][n][0] + bb.x);
            h4.y = f2b(acc[m][n][1] + bb.y);
            h4.z = f2b(acc[m][n][2] + bb.z);
            h4.w = f2b(acc[m][n][3] + bb.w);
            *(ushort4*)(Oh + ((size_t)b * 130 + s + 1) * 512 + c) = h4;
        }
    }
}

// ---------------- K3: GLU conv layer, single-bf16 MFMA GEMM ----------------
// Per ci0 (16 iters): stage A = 3 kr sub-tiles (128x32) + B = H slab rows
// 0..143 x 32ci.  48 MFMA per barrier pair per wave.
__global__ __launch_bounds__(256) void k_conv_gemm(
    const ushort_t* __restrict__ Wt, const ushort_t* __restrict__ Ht,
    const float* __restrict__ cb,          // conv_b + l*1024
    ushort_t* __restrict__ Ot)
{
    __shared__ short lds[17408];           // A: 3*4096; B: 4608; epilogue needs 8704 fl
    short* AS = lds;
    short* BS = lds + 12288;
    float* g_lds = (float*)lds;            // epilogue aliases (34816 B total)

    const int bid  = blockIdx.x;
    const int co0  = (bid & 7) << 6;       // 64 output channels; co == XCD id
    const int b    = bid >> 3;
    const int t    = threadIdx.x;
    const int w    = t >> 6;
    const int lane = t & 63;
    const int wr   = w >> 1;               // 0: a-rows, 1: g-rows
    const int wc   = w & 1;                // s half

    // A staging: wave w covers rows w*32..w*32+31 of each 128x32 sub-tile
    const int srow0 = (w << 5) + (lane >> 2);
    const int srow1 = srow0 + 16;
    const int j0 = (lane & 3) ^ ((srow0 >> 1) & 3);
    const int j1 = (lane & 3) ^ ((srow1 >> 1) & 3);
    const int coA0 = (srow0 < 64) ? (co0 + srow0) : (512 + co0 + srow0 - 64);
    const int coA1 = (srow1 < 64) ? (co0 + srow1) : (512 + co0 + srow1 - 64);
    const size_t aoff0 = (size_t)coA0 * 1536 + j0 * 8;
    const size_t aoff1 = (size_t)coA1 * 1536 + j1 * 8;
    const int lrow = lane >> 2;
    const int wofs = w << 10;

    const int lr = lane & 15, kg = lane >> 4;
    int aro[4];
    #pragma unroll
    for (int m = 0; m < 4; ++m) { int r = (wr << 6) + (m << 4) + lr; aro[m] = (r << 5) + ((kg ^ ((r >> 1) & 3)) << 3); }
    int bro[3][4];
    #pragma unroll
    for (int kr = 0; kr < 3; ++kr)
        #pragma unroll
        for (int n = 0; n < 4; ++n) {
            int r = (wc << 6) + (n << 4) + lr + kr;
            bro[kr][n] = (r << 5) + ((kg ^ ((r >> 1) & 3)) << 3);
        }

    f32x4 acc[4][4];
    #pragma unroll
    for (int m = 0; m < 4; ++m)
        #pragma unroll
        for (int n = 0; n < 4; ++n) acc[m][n] = (f32x4){0.f, 0.f, 0.f, 0.f};

    for (int ci0 = 0; ci0 < 512; ci0 += 32) {
        // ---- stage A: 3 kr sub-tiles ----
        #pragma unroll
        for (int kr = 0; kr < 3; ++kr) {
            gload16(Wt + aoff0 + kr * 512 + ci0, AS + kr * 4096 + wofs);
            gload16(Wt + aoff1 + kr * 512 + ci0, AS + kr * 4096 + wofs + 512);
        }
        // ---- stage B: H rows 0..143 (shared across kr; rows >129 unused) ----
        for (int i = w; i < 9; i += 4) {
            const int rr = (i << 4) + lrow;
            const int sl = (lane & 3) ^ ((rr >> 1) & 3);
            gload16(Ht + ((size_t)b * 130 + rr) * 512 + ci0 + sl * 8, BS + (i << 9));
        }
        __syncthreads();
        #pragma unroll
        for (int kr = 0; kr < 3; ++kr) {
            const short* A_h = AS + kr * 4096;
            bf16x8 avh[4], bvh[4];
            #pragma unroll
            for (int m = 0; m < 4; ++m) avh[m] = *(const bf16x8*)(A_h + aro[m]);
            #pragma unroll
            for (int n = 0; n < 4; ++n) bvh[n] = *(const bf16x8*)(BS + bro[kr][n]);
            #pragma unroll
            for (int m = 0; m < 4; ++m)
                #pragma unroll
                for (int n = 0; n < 4; ++n)
                    acc[m][n] = __builtin_amdgcn_mfma_f32_16x16x32_bf16(avh[m], bvh[n], acc[m][n], 0, 0, 0);
        }
        __syncthreads();
    }

    // ---- fused GLU epilogue: g-waves hand their acc to a-waves via LDS ----
    const float rs = 0.70710678118654752f;
    if (wr == 1) {
        #pragma unroll
        for (int m = 0; m < 4; ++m) {
            const int co_l = (m << 4) + (kg << 2);
            float4 bg = *(const float4*)(cb + 512 + co0 + co_l);
            #pragma unroll
            for (int n = 0; n < 4; ++n) {
                const int s_l = (wc << 6) + (n << 4) + lr;
                float4 gv;
                gv.x = acc[m][n][0] + bg.x;
                gv.y = acc[m][n][1] + bg.y;
                gv.z = acc[m][n][2] + bg.z;
                gv.w = acc[m][n][3] + bg.w;
                *(float4*)&g_lds[s_l * 68 + co_l] = gv;
            }
        }
    }
    __syncthreads();
    if (wr == 0) {
        #pragma unroll
        for (int m = 0; m < 4; ++m) {
            const int co_l = (m << 4) + (kg << 2);
            float4 ba = *(const float4*)(cb + co0 + co_l);
            #pragma unroll
            for (int n = 0; n < 4; ++n) {
                const int s_l = (wc << 6) + (n << 4) + lr;
                float4 gv = *(const float4*)&g_lds[s_l * 68 + co_l];
                size_t dst = ((size_t)b * 130 + s_l + 1) * 512 + co0 + co_l;
                ushort4 rh = *(const ushort4*)(Ht + dst);
                float a0 = acc[m][n][0] + ba.x, g0 = gv.x;
                float a1 = acc[m][n][1] + ba.y, g1 = gv.y;
                float a2 = acc[m][n][2] + ba.z, g2 = gv.z;
                float a3 = acc[m][n][3] + ba.w, g3 = gv.w;
                ushort4 h4;
                h4.x = f2b((a0 / (1.f + expf(-g0)) + b2f(rh.x)) * rs);
                h4.y = f2b((a1 / (1.f + expf(-g1)) + b2f(rh.y)) * rs);
                h4.z = f2b((a2 / (1.f + expf(-g2)) + b2f(rh.z)) * rs);
                h4.w = f2b((a3 / (1.f + expf(-g3)) + b2f(rh.w)) * rs);
                *(ushort4*)(Ot + dst) = h4;
            }
        }
    }
}

// ---------------- K4: emissions 512 -> 20 (h in (b,s,c) bf16) --------------
__global__ __launch_bounds__(256) void k_emis2(const ushort_t* __restrict__ hh,
                                               const float* __restrict__ fc_w,
                                               const float* __restrict__ fc_b,
                                               float* __restrict__ emis) {
    __shared__ float hsE[128][33];
    __shared__ float wsE[32][20];
    int b = blockIdx.x, t = threadIdx.x;
    int tg = t >> 7, s = t & 127;
    float acc[10] = {};
    for (int c0 = 0; c0 < C_; c0 += 32) {
        #pragma unroll
        for (int i = 0; i < 2; ++i) {
            int flat = t + i * 256;
            int row = flat >> 2, ch = (flat & 3) * 8;
            u16x8 vh = *(const u16x8*)(hh + ((size_t)b * 130 + row + 1) * 512 + c0 + ch);
            #pragma unroll
            for (int k = 0; k < 8; ++k) hsE[row][ch + k] = b2f(vh[k]);
        }
        for (int idx = t; idx < 32 * NT_; idx += 256) {
            int kk = idx / NT_, tt = idx - kk * NT_;
            wsE[kk][tt] = fc_w[(size_t)(c0 + kk) * NT_ + tt];
        }
        __syncthreads();
        #pragma unroll
        for (int kk = 0; kk < 32; ++kk) {
            float hv = hsE[s][kk];
            #pragma unroll
            for (int j = 0; j < 10; ++j) acc[j] += hv * wsE[kk][tg * 10 + j];
        }
        __syncthreads();
    }
    #pragma unroll
    for (int j = 0; j < 10; ++j)
        emis[((size_t)s * B_ + b) * NT_ + tg * 10 + j] = acc[j] + fc_b[tg * 10 + j];
}

// ---------------- K5: fused CRF NLL (wave 0) + Viterbi (wave 1) ------------
__global__ __launch_bounds__(128) void k_crf(const float* __restrict__ emis,
                                             const int* __restrict__ words,
                                             const int* __restrict__ tags,
                                             const float* __restrict__ tstart,
                                             const float* __restrict__ tend,
                                             const float* __restrict__ ttrans,
                                             float* __restrict__ nll,
                                             float* __restrict__ out) {
    __shared__ float e_lds[S_ * NT_];          // 10240 B
    __shared__ int   bp_lds[(S_ - 1) * NT_];   // 10160 B
    const int b = blockIdx.x;
    const int t = threadIdx.x;

    for (int idx = t; idx < S_ * NT_; idx += 128) {
        int tt = idx / NT_, j = idx - tt * NT_;
        e_lds[idx] = emis[((size_t)tt * B_ + b) * NT_ + j];
    }
    __syncthreads();

    const int ln = t & 63;
    unsigned long long mlo = __ballot(words[ln * B_ + b] != 0);
    unsigned long long mhi = __ballot(words[(64 + ln) * B_ + b] != 0);
    const bool act = ln < NT_;
    const int jc = act ? ln : 0;
    float tc[NT_];
    #pragma unroll
    for (int i = 0; i < NT_; ++i) tc[i] = act ? ttrans[i * NT_ + ln] : 0.f;

    if (t < 64) {
        float part = 0.f;
        for (int tt = ln; tt < S_; tt += 64) {
            int tgc = tags[tt * B_ + b];
            bool m = ((tt < 64 ? (mlo >> tt) : (mhi >> (tt - 64))) & 1ull) != 0;
            if (tt == 0) {
                part += tstart[tgc] + e_lds[tgc];
            } else if (m) {
                int tgp = tags[(tt - 1) * B_ + b];
                part += ttrans[tgp * NT_ + tgc] + e_lds[tt * NT_ + tgc];
            }
        }
        #pragma unroll
        for (int o = 32; o >= 1; o >>= 1) part += __shfl_down(part, o);

        float aown = tstart[jc] + e_lds[jc];
        float al[NT_];
        #pragma unroll
        for (int i = 0; i < NT_; ++i) al[i] = __shfl(aown, i);
        for (int tt = 1; tt < S_; ++tt) {
            float v[NT_];
            #pragma unroll
            for (int i = 0; i < NT_; ++i) v[i] = al[i] + tc[i];
            float mx = max20(v);
            float ex[NT_];
            #pragma unroll
            for (int i = 0; i < NT_; ++i) ex[i] = __builtin_amdgcn_exp2f((v[i] - mx) * LOG2E_);
            float sm = sum20(ex);
            float anew = mx + __builtin_amdgcn_logf(sm) * LN2_ + e_lds[tt * NT_ + jc];
            bool m = ((tt < 64 ? (mlo >> tt) : (mhi >> (tt - 64))) & 1ull) != 0;
            aown = m ? anew : aown;
            #pragma unroll
            for (int i = 0; i < NT_; ++i) al[i] = __shfl(aown, i);
        }
        float f[NT_];
        #pragma unroll
        for (int i = 0; i < NT_; ++i) f[i] = al[i] + tend[i];
        float mx2 = max20(f);
        float ex2[NT_];
        #pragma unroll
        for (int i = 0; i < NT_; ++i) ex2[i] = __builtin_amdgcn_exp2f((f[i] - mx2) * LOG2E_);
        float logz = mx2 + __builtin_amdgcn_logf(sum20(ex2)) * LN2_;
        if (ln == 0) {
            int cnt = __popcll(mlo) + __popcll(mhi);
            float num = part + tend[tags[(cnt - 1) * B_ + b]];
            nll[b] = logz - num;
        }
    } else {
        float sown = tstart[jc] + e_lds[jc];
        float sc[NT_];
        #pragma unroll
        for (int i = 0; i < NT_; ++i) sc[i] = __shfl(sown, i);
        for (int tt = 1; tt < S_; ++tt) {
            float best = sc[0] + tc[0];
            int bi = 0;
            #pragma unroll
            for (int i = 1; i < NT_; ++i) {    // strict > keeps FIRST max (jnp.argmax)
                float vv = sc[i] + tc[i];
                if (vv > best) { best = vv; bi = i; }
            }
            bool m = ((tt < 64 ? (mlo >> tt) : (mhi >> (tt - 64))) & 1ull) != 0;
            float nxt = best + e_lds[tt * NT_ + jc];
            sown = m ? nxt : sown;
            if (act) bp_lds[(tt - 1) * NT_ + ln] = m ? bi : ln;
            #pragma unroll
            for (int i = 0; i < NT_; ++i) sc[i] = __shfl(sown, i);
        }
        if (ln == 0) {
            float best = sc[0] + tend[0];
            int bt = 0;
            for (int i = 1; i < NT_; ++i) {
                float vv = sc[i] + tend[i];
                if (vv > best) { best = vv; bt = i; }
            }
            int tag = bt;
            for (int tt = S_ - 1; tt >= 1; --tt) {
                out[tt * B_ + b] = (float)tag;
                tag = bp_lds[(tt - 1) * NT_ + tag];
            }
            out[b] = (float)tag;
        }
    }
}

// ---------------- K7: final loss reduce ------------------------------------
__global__ void k_loss(const float* __restrict__ nll, float* __restrict__ out) {
    float v = nll[threadIdx.x];
    #pragma unroll
    for (int o = 32; o >= 1; o >>= 1) v += __shfl_down(v, o);
    if (threadIdx.x == 0) out[S_ * B_] = v;
}

extern "C" void kernel_launch(void* const* d_in, const int* in_sizes, int n_in,
                              void* d_out, int out_size, void* d_ws, size_t ws_size,
                              hipStream_t stream) {
    (void)in_sizes; (void)n_in; (void)out_size; (void)ws_size;
    const int*   words     = (const int*)d_in[0];
    const int*   chars     = (const int*)d_in[1];
    const int*   tags      = (const int*)d_in[2];
    const float* word_emb  = (const float*)d_in[3];
    const float* char_emb  = (const float*)d_in[4];
    const float* ccw       = (const float*)d_in[5];
    const float* ccb       = (const float*)d_in[6];
    const float* lin_w     = (const float*)d_in[7];
    const float* lin_b     = (const float*)d_in[8];
    const float* conv_w    = (const float*)d_in[9];
    const float* conv_b    = (const float*)d_in[10];
    const float* fc_w      = (const float*)d_in[11];
    const float* fc_b      = (const float*)d_in[12];
    const float* crf_start = (const float*)d_in[13];
    const float* crf_end   = (const float*)d_in[14];
    const float* crf_trans = (const float*)d_in[15];

    float* ws   = (float*)d_ws;
    float* wf   = ws + WF_OFF;
    float* em   = ws + EM_OFF;
    float* nll  = ws + NLL_OFF;
    ushort_t* h0  = (ushort_t*)(ws + H0_OFF);
    ushort_t* h1  = (ushort_t*)(ws + H1_OFF);
    ushort_t* wsp = (ushort_t*)(ws + WS_OFF);
    ushort_t* lwp = (ushort_t*)(ws + LW_OFF);
    ushort_t* fsp = (ushort_t*)(ws + FS_OFF);
    float* out  = (float*)d_out;

    k_word_gather<<<S_ * B_, 128, 0, stream>>>(words, word_emb, wf);
    k_char_cnn<<<B_ * S_, 128, 0, stream>>>(chars, char_emb, ccw, ccb, wf);
    k_split_w<<<18432, 256, 0, stream>>>(conv_w, wsp);
    k_split_lw<<<KL_, 512, 0, stream>>>(lin_w, lwp);
    k_split_wf<<<S_ * B_, 224, 0, stream>>>(wf, fsp);
    k_lin_gemm<<<256, 256, 0, stream>>>(lwp, fsp, lin_b, h0);
    k_zero_pad<<<dim3(64, 2), 256, 0, stream>>>(h0, h1);

    k_conv_gemm<<<512, 256, 0, stream>>>(wsp,              h0, conv_b,        h1);
    k_conv_gemm<<<512, 256, 0, stream>>>(wsp + WLAYER,     h1, conv_b + 1024, h0);
    k_conv_gemm<<<512, 256, 0, stream>>>(wsp + 2*WLAYER,   h0, conv_b + 2048, h1);

    k_emis2<<<B_, 256, 0, stream>>>(h1, fc_w, fc_b, em);
    k_crf<<<B_, 128, 0, stream>>>(em, words, tags, crf_start, crf_end, crf_trans, nll, out);
    k_loss<<<1, 64, 0, stream>>>(nll, out);
}